// Round 1
// baseline (281.244 us; speedup 1.0000x reference)
//
#include <hip/hip_runtime.h>
#include <stdint.h>

// Pipeline: cvt x,z -> bf16; pack weights; 3x GEMM (Q,K,V) with bf16 MFMA;
// flash attention (causal, online softmax); output GEMM -> f32.
// B=8 TX=TZ=1024 DX=DZ=1024 DATT=DMID=64 H=16 DOUT=1024.

typedef float    f32x4  __attribute__((ext_vector_type(4)));
typedef __bf16   bf16x8 __attribute__((ext_vector_type(8)));
typedef unsigned short u16x4 __attribute__((ext_vector_type(4)));
typedef unsigned short u16x8 __attribute__((ext_vector_type(8)));

__device__ __forceinline__ unsigned short f2bf(float f) {
  unsigned int u = __float_as_uint(f);
  u += 0x7fffu + ((u >> 16) & 1u);   // RNE (no NaN handling; none expected)
  return (unsigned short)(u >> 16);
}

__device__ __forceinline__ void gload16(const void* g, void* s) {
  // global -> LDS direct DMA, 16B/lane; LDS dest = wave-uniform base + lane*16.
  const __attribute__((address_space(1))) unsigned int* gp =
      (const __attribute__((address_space(1))) unsigned int*)(uintptr_t)g;
  __attribute__((address_space(3))) unsigned int* lp =
      (__attribute__((address_space(3))) unsigned int*)(unsigned int)(uintptr_t)s;
  __builtin_amdgcn_global_load_lds(gp, lp, 16, 0, 0);
}

__device__ __forceinline__ f32x4 mfma16(bf16x8 a, bf16x8 b, f32x4 c) {
  return __builtin_amdgcn_mfma_f32_16x16x32_bf16(a, b, c, 0, 0, 0);
}

// ---------------- prep kernels ----------------

__global__ __launch_bounds__(256) void k_cvt(const float* __restrict__ in,
                                             unsigned short* __restrict__ out, int n8) {
  int i = blockIdx.x * 256 + threadIdx.x;
  int stride = gridDim.x * 256;
  for (; i < n8; i += stride) {
    const f32x4* p = (const f32x4*)(in + (size_t)i * 8);
    f32x4 a = p[0], b = p[1];
    u16x8 o;
    o[0] = f2bf(a[0]); o[1] = f2bf(a[1]); o[2] = f2bf(a[2]); o[3] = f2bf(a[3]);
    o[4] = f2bf(b[0]); o[5] = f2bf(b[1]); o[6] = f2bf(b[2]); o[7] = f2bf(b[3]);
    *(u16x8*)(out + (size_t)i * 8) = o;
  }
}

// Wq/Wk/Wv [H][DX][64] f32 -> Wt [H*64+e][DX] bf16   (K-contiguous NT layout)
__global__ __launch_bounds__(256) void k_packw(const float* __restrict__ Wq,
                                               const float* __restrict__ Wk,
                                               const float* __restrict__ Wv,
                                               unsigned short* __restrict__ Oq,
                                               unsigned short* __restrict__ Ok,
                                               unsigned short* __restrict__ Ov) {
  __shared__ float tile[64][65];
  const float* W = blockIdx.y == 0 ? Wq : (blockIdx.y == 1 ? Wk : Wv);
  unsigned short* O = blockIdx.y == 0 ? Oq : (blockIdx.y == 1 ? Ok : Ov);
  const int h = blockIdx.x;
  const int t = threadIdx.x;
  const int ee = t & 63, r0 = t >> 6;
  for (int d0 = 0; d0 < 1024; d0 += 64) {
    __syncthreads();
    for (int dd = r0; dd < 64; dd += 4)
      tile[dd][ee] = W[(h * 1024 + d0 + dd) * 64 + ee];
    __syncthreads();
    const int d = t & 63, e0 = t >> 6;
    for (int e = e0; e < 64; e += 4)
      O[(h * 64 + e) * 1024 + d0 + d] = f2bf(tile[d][e]);
  }
}

// Wp [1024][1024] f32 -> Wpt [n][k] bf16 (transposed)
__global__ __launch_bounds__(256) void k_packp(const float* __restrict__ W,
                                               unsigned short* __restrict__ O) {
  __shared__ float tile[64][65];
  const int k0 = blockIdx.x * 64, n0 = blockIdx.y * 64;
  const int t = threadIdx.x;
  const int nn = t & 63, r0 = t >> 6;
  for (int kk = r0; kk < 64; kk += 4)
    tile[kk][nn] = W[(k0 + kk) * 1024 + n0 + nn];
  __syncthreads();
  const int kk = t & 63, e0 = t >> 6;
  for (int n2 = e0; n2 < 64; n2 += 4)
    O[(n0 + n2) * 1024 + k0 + kk] = f2bf(tile[kk][n2]);
}

// ---------------- GEMM: C[8192x1024] = A[8192x1024] * Bt[1024x1024]^T + bias ----------------
// mode 0: bf16 out to [bh][x][64] (Q/K), scaled by oscale
// mode 2: bf16 out to [bh][e][z]  (V transposed)
// mode 3: f32 out, row-major (final projection)
__global__ __launch_bounds__(256) void k_gemm(const unsigned short* __restrict__ A,
                                              const unsigned short* __restrict__ Bt,
                                              const float* __restrict__ bias,
                                              void* __restrict__ outp,
                                              int mode, float oscale) {
  __shared__ unsigned short As[4096];  // 128 rows x 32 k, swizzled (8 KB)
  __shared__ unsigned short Bs[4096];
  const int tid = threadIdx.x;
  const int l = tid & 63, w = tid >> 6;
  const int lrow = l & 15, lk = l >> 4;
  const int wr = (w >> 1) * 64, wc = (w & 1) * 64;
  const int brow = blockIdx.x * 128, bcol = blockIdx.y * 128;

  // staging: thread t -> row t>>2 (+64 for issue 1), 16B slot t&3; XOR-pre-swizzled source
  const int arow = tid >> 2;
  const int asrc = ((tid & 3) ^ ((arow >> 1) & 3)) * 8;
  const unsigned short* ag0 = A + (brow + arow) * 1024 + asrc;
  const unsigned short* ag1 = ag0 + 64 * 1024;
  const unsigned short* bg0 = Bt + (bcol + arow) * 1024 + asrc;
  const unsigned short* bg1 = bg0 + 64 * 1024;
  char* asb = (char*)As + w * 1024;
  char* bsb = (char*)Bs + w * 1024;

  int aoff[4], boff[4];
#pragma unroll
  for (int m = 0; m < 4; m++) {
    int row = wr + m * 16 + lrow;
    aoff[m] = row * 64 + ((lk ^ ((row >> 1) & 3)) << 4);
    int col = wc + m * 16 + lrow;
    boff[m] = col * 64 + ((lk ^ ((col >> 1) & 3)) << 4);
  }

  f32x4 acc[4][4];
#pragma unroll
  for (int n = 0; n < 4; n++) {
    float bv = bias[bcol + wc + n * 16 + lrow];
#pragma unroll
    for (int m = 0; m < 4; m++) acc[m][n] = (f32x4){bv, bv, bv, bv};
  }

  for (int kt = 0; kt < 32; kt++) {
    __syncthreads();
    gload16(ag0 + kt * 32, asb);
    gload16(ag1 + kt * 32, asb + 4096);
    gload16(bg0 + kt * 32, bsb);
    gload16(bg1 + kt * 32, bsb + 4096);
    __syncthreads();
    bf16x8 af[4], bfr[4];
#pragma unroll
    for (int m = 0; m < 4; m++) af[m] = *(const bf16x8*)((const char*)As + aoff[m]);
#pragma unroll
    for (int n = 0; n < 4; n++) bfr[n] = *(const bf16x8*)((const char*)Bs + boff[n]);
#pragma unroll
    for (int m = 0; m < 4; m++)
#pragma unroll
      for (int n = 0; n < 4; n++)
        acc[m][n] = mfma16(af[m], bfr[n], acc[m][n]);
  }

  if (mode == 0) {
    unsigned short* C = (unsigned short*)outp;
#pragma unroll
    for (int m = 0; m < 4; m++) {
      int r = brow + wr + m * 16 + 4 * lk;
#pragma unroll
      for (int n = 0; n < 4; n++) {
        int c = bcol + wc + n * 16 + lrow;
        unsigned short* p = C + ((r >> 10) * 16 + (c >> 6)) * 65536 + (r & 1023) * 64 + (c & 63);
#pragma unroll
        for (int j = 0; j < 4; j++) p[j * 64] = f2bf(acc[m][n][j] * oscale);
      }
    }
  } else if (mode == 2) {
    unsigned short* C = (unsigned short*)outp;
#pragma unroll
    for (int m = 0; m < 4; m++) {
      int r = brow + wr + m * 16 + 4 * lk;
#pragma unroll
      for (int n = 0; n < 4; n++) {
        int c = bcol + wc + n * 16 + lrow;
        u16x4 o;
#pragma unroll
        for (int j = 0; j < 4; j++) o[j] = f2bf(acc[m][n][j]);
        *(u16x4*)(C + ((r >> 10) * 16 + (c >> 6)) * 65536 + (c & 63) * 1024 + (r & 1023)) = o;
      }
    }
  } else {
    float* C = (float*)outp;
#pragma unroll
    for (int m = 0; m < 4; m++) {
      int r = brow + wr + m * 16 + 4 * lk;
#pragma unroll
      for (int n = 0; n < 4; n++) {
        int c = bcol + wc + n * 16 + lrow;
#pragma unroll
        for (int j = 0; j < 4; j++) C[(r + j) * 1024 + c] = acc[m][n][j];
      }
    }
  }
}

// ---------------- flash attention ----------------
// Q [bh][1024][64] (prescaled by 0.125*log2e), K [bh][1024][64], Vt [bh][64][1024]
// -> Y [b*1024+x][h*64+e] bf16. Causal. Block: 4 waves x 16 q-rows; KV tiles of 64.
__global__ __launch_bounds__(256) void k_attn(const unsigned short* __restrict__ Qh,
                                              const unsigned short* __restrict__ Kh,
                                              const unsigned short* __restrict__ Vth,
                                              unsigned short* __restrict__ Y) {
  __shared__ unsigned short Ks[4096];  // 64 z x 64 e, swizzled
  __shared__ unsigned short Vs[4096];  // 64 e x 64 z, swizzled
  __shared__ unsigned short Ps[4096];  // per-wave 16 q x 64 z, swizzled

  const int tid = threadIdx.x, l = tid & 63, w = tid >> 6;
  const int lrow = l & 15, lk = l >> 4;
  const int bh = blockIdx.y;
  const int q0 = (15 - blockIdx.x) * 64;  // largest tiles dispatched first

  const unsigned short* Qb = Qh + bh * 65536;
  const unsigned short* Kb = Kh + bh * 65536;
  const unsigned short* Vb = Vth + bh * 65536;

  bf16x8 qf[2];
  {
    const unsigned short* qp = Qb + (q0 + w * 16 + lrow) * 64 + lk * 8;
    qf[0] = *(const bf16x8*)qp;
    qf[1] = *(const bf16x8*)(qp + 32);
  }

  float mrow[4], lsum[4];
  f32x4 yacc[4];
#pragma unroll
  for (int j = 0; j < 4; j++) { mrow[j] = -__builtin_inff(); lsum[j] = 0.f; }
#pragma unroll
  for (int ef = 0; ef < 4; ef++) yacc[ef] = (f32x4){0.f, 0.f, 0.f, 0.f};

  const int srow = tid >> 3;
  const int swz = ((tid & 7) ^ (srow & 7)) * 8;
  const unsigned short* kg0 = Kb + srow * 64 + swz;
  const unsigned short* kg1 = Kb + (srow + 32) * 64 + swz;
  const unsigned short* vg0 = Vb + srow * 1024 + swz;
  const unsigned short* vg1 = Vb + (srow + 32) * 1024 + swz;
  char* ksb = (char*)Ks + w * 1024;
  char* vsb = (char*)Vs + w * 1024;
  unsigned short* pw = Ps + w * 1024;

  const int nt = q0 / 64 + 1;
  for (int t = 0; t < nt; t++) {
    const int z0 = t * 64;
    __syncthreads();
    gload16(kg0 + z0 * 64, ksb);
    gload16(kg1 + z0 * 64, ksb + 4096);
    gload16(vg0 + z0, vsb);
    gload16(vg1 + z0, vsb + 4096);
    __syncthreads();

    // S = Q K^T  (already in log2 domain via Q prescale)
    f32x4 s[4];
#pragma unroll
    for (int zf = 0; zf < 4; zf++) {
      s[zf] = (f32x4){0.f, 0.f, 0.f, 0.f};
      int zr = zf * 16 + lrow;
#pragma unroll
      for (int kf = 0; kf < 2; kf++) {
        bf16x8 kfr = *(const bf16x8*)((const char*)Ks + zr * 128 + (((kf * 4 + lk) ^ (zr & 7)) << 4));
        s[zf] = mfma16(qf[kf], kfr, s[zf]);
      }
    }

    if (t == nt - 1) {  // diagonal tile: mask z > q
      int qloc = w * 16 + 4 * lk;
#pragma unroll
      for (int zf = 0; zf < 4; zf++) {
        int zloc = zf * 16 + lrow;
#pragma unroll
        for (int j = 0; j < 4; j++)
          if (zloc > qloc + j) s[zf][j] = -__builtin_inff();
      }
    }

    // online softmax (rows live across 16 lanes: shfl_xor 1,2,4,8)
#pragma unroll
    for (int j = 0; j < 4; j++) {
      float rm = fmaxf(fmaxf(s[0][j], s[1][j]), fmaxf(s[2][j], s[3][j]));
      rm = fmaxf(rm, __shfl_xor(rm, 1));
      rm = fmaxf(rm, __shfl_xor(rm, 2));
      rm = fmaxf(rm, __shfl_xor(rm, 4));
      rm = fmaxf(rm, __shfl_xor(rm, 8));
      float mn = fmaxf(mrow[j], rm);
      float a = __builtin_amdgcn_exp2f(mrow[j] - mn);
      mrow[j] = mn;
      float rs = 0.f;
#pragma unroll
      for (int zf = 0; zf < 4; zf++) {
        float p = __builtin_amdgcn_exp2f(s[zf][j] - mn);
        s[zf][j] = p;
        rs += p;
      }
      rs += __shfl_xor(rs, 1);
      rs += __shfl_xor(rs, 2);
      rs += __shfl_xor(rs, 4);
      rs += __shfl_xor(rs, 8);
      lsum[j] = lsum[j] * a + rs;
#pragma unroll
      for (int ef = 0; ef < 4; ef++) yacc[ef][j] *= a;
    }

    // P -> per-wave LDS (bf16, swizzled) to re-layout into A-fragments
#pragma unroll
    for (int zf = 0; zf < 4; zf++) {
      int zc = zf * 16 + lrow;
      int zp = zc >> 3;
#pragma unroll
      for (int j = 0; j < 4; j++) {
        int q = 4 * lk + j;
        *(unsigned short*)((char*)pw + q * 128 + ((zp ^ (q & 7)) << 4) + (zc & 7) * 2) = f2bf(s[zf][j]);
      }
    }
    bf16x8 pf[2];
#pragma unroll
    for (int kf = 0; kf < 2; kf++) {
      int zp = kf * 4 + lk;
      pf[kf] = *(const bf16x8*)((const char*)pw + lrow * 128 + ((zp ^ (lrow & 7)) << 4));
    }
    // y += P V
#pragma unroll
    for (int ef = 0; ef < 4; ef++) {
      int e = ef * 16 + lrow;
#pragma unroll
      for (int kf = 0; kf < 2; kf++) {
        bf16x8 vf = *(const bf16x8*)((const char*)Vs + e * 128 + (((kf * 4 + lk) ^ (e & 7)) << 4));
        yacc[ef] = mfma16(pf[kf], vf, yacc[ef]);
      }
    }
  }

  const int b = bh >> 4, h = bh & 15;
#pragma unroll
  for (int ef = 0; ef < 4; ef++) {
    int col = h * 64 + ef * 16 + lrow;
#pragma unroll
    for (int j = 0; j < 4; j++) {
      int x = q0 + w * 16 + 4 * lk + j;
      Y[(b * 1024 + x) * 1024 + col] = f2bf(yacc[ef][j] / lsum[j]);
    }
  }
}

// ---------------- launch ----------------
extern "C" void kernel_launch(void* const* d_in, const int* in_sizes, int n_in,
                              void* d_out, int out_size, void* d_ws, size_t ws_size,
                              hipStream_t stream) {
  const float* x  = (const float*)d_in[0];
  const float* z  = (const float*)d_in[1];
  const float* Wq = (const float*)d_in[2];
  const float* bq = (const float*)d_in[3];
  const float* Wk = (const float*)d_in[4];
  const float* bk = (const float*)d_in[5];
  const float* Wv = (const float*)d_in[6];
  const float* bv = (const float*)d_in[7];
  const float* Wp = (const float*)d_in[8];
  const float* bp = (const float*)d_in[9];
  (void)in_sizes; (void)n_in; (void)out_size; (void)ws_size;

  char* ws = (char*)d_ws;
  unsigned short* Xb  = (unsigned short*)(ws + 0);         // 16 MB (re-used as Y after QKV GEMMs)
  unsigned short* Zb  = (unsigned short*)(ws + 16777216);  // 16 MB
  unsigned short* Wqt = (unsigned short*)(ws + 33554432);  // 2 MB
  unsigned short* Wkt = (unsigned short*)(ws + 35651584);  // 2 MB
  unsigned short* Wvt = (unsigned short*)(ws + 37748736);  // 2 MB
  unsigned short* Wpt = (unsigned short*)(ws + 39845888);  // 2 MB
  unsigned short* Qp  = (unsigned short*)(ws + 41943040);  // 16 MB
  unsigned short* Kp  = (unsigned short*)(ws + 58720256);  // 16 MB
  unsigned short* Vtp = (unsigned short*)(ws + 75497472);  // 16 MB  (end: 92274688)

  k_cvt<<<dim3(2048), dim3(256), 0, stream>>>(x, Xb, 1048576);
  k_cvt<<<dim3(2048), dim3(256), 0, stream>>>(z, Zb, 1048576);
  k_packw<<<dim3(16, 3), dim3(256), 0, stream>>>(Wq, Wk, Wv, Wqt, Wkt, Wvt);
  k_packp<<<dim3(16, 16), dim3(256), 0, stream>>>(Wp, Wpt);

  const float QSCALE = 0.125f * 1.4426950408889634f;  // 1/sqrt(64) * log2(e)
  k_gemm<<<dim3(64, 8), dim3(256), 0, stream>>>(Xb, Wqt, bq, Qp, 0, QSCALE);
  k_gemm<<<dim3(64, 8), dim3(256), 0, stream>>>(Zb, Wkt, bk, Kp, 0, 1.0f);
  k_gemm<<<dim3(64, 8), dim3(256), 0, stream>>>(Zb, Wvt, bv, Vtp, 2, 1.0f);

  k_attn<<<dim3(16, 128), dim3(256), 0, stream>>>(Qp, Kp, Vtp, Xb /*Y*/);

  k_gemm<<<dim3(64, 8), dim3(256), 0, stream>>>(Xb, Wpt, bp, d_out, 3, 1.0f);
}

// Round 4
// 269.744 us; speedup vs baseline: 1.0426x; 1.0426x over previous
//
#include <hip/hip_runtime.h>
#include <stdint.h>

// Pipeline: cvt x,z -> bf16; pack weights; 3x GEMM (Q,K,V) with bf16 MFMA;
// flash attention (causal, online softmax, round-1-validated dataflow, 32q/wave);
// output GEMM -> f32.
// B=8 TX=TZ=1024 DX=DZ=1024 DATT=DMID=64 H=16 DOUT=1024.

typedef float    f32x4  __attribute__((ext_vector_type(4)));
typedef __bf16   bf16x8 __attribute__((ext_vector_type(8)));
typedef unsigned short u16x4 __attribute__((ext_vector_type(4)));
typedef unsigned short u16x8 __attribute__((ext_vector_type(8)));

#define MASKNEG (-3.0e38f)

__device__ __forceinline__ unsigned short f2bf(float f) {
  unsigned int u = __float_as_uint(f);
  u += 0x7fffu + ((u >> 16) & 1u);   // RNE
  return (unsigned short)(u >> 16);
}

__device__ __forceinline__ void gload16(const void* g, void* s) {
  const __attribute__((address_space(1))) unsigned int* gp =
      (const __attribute__((address_space(1))) unsigned int*)(uintptr_t)g;
  __attribute__((address_space(3))) unsigned int* lp =
      (__attribute__((address_space(3))) unsigned int*)(unsigned int)(uintptr_t)s;
  __builtin_amdgcn_global_load_lds(gp, lp, 16, 0, 0);
}

__device__ __forceinline__ f32x4 mfma16(bf16x8 a, bf16x8 b, f32x4 c) {
  return __builtin_amdgcn_mfma_f32_16x16x32_bf16(a, b, c, 0, 0, 0);
}

// ---------------- prep kernels ----------------

__global__ __launch_bounds__(256) void k_cvt(const float* __restrict__ in,
                                             unsigned short* __restrict__ out, int n8) {
  int i = blockIdx.x * 256 + threadIdx.x;
  int stride = gridDim.x * 256;
  for (; i < n8; i += stride) {
    const f32x4* p = (const f32x4*)(in + (size_t)i * 8);
    f32x4 a = p[0], b = p[1];
    u16x8 o;
    o[0] = f2bf(a[0]); o[1] = f2bf(a[1]); o[2] = f2bf(a[2]); o[3] = f2bf(a[3]);
    o[4] = f2bf(b[0]); o[5] = f2bf(b[1]); o[6] = f2bf(b[2]); o[7] = f2bf(b[3]);
    *(u16x8*)(out + (size_t)i * 8) = o;
  }
}

// Wq/Wk/Wv [H][DX][64] f32 -> Wt [H*64+e][DX] bf16   (K-contiguous NT layout)
__global__ __launch_bounds__(256) void k_packw(const float* __restrict__ Wq,
                                               const float* __restrict__ Wk,
                                               const float* __restrict__ Wv,
                                               unsigned short* __restrict__ Oq,
                                               unsigned short* __restrict__ Ok,
                                               unsigned short* __restrict__ Ov) {
  __shared__ float tile[64][65];
  const float* W = blockIdx.y == 0 ? Wq : (blockIdx.y == 1 ? Wk : Wv);
  unsigned short* O = blockIdx.y == 0 ? Oq : (blockIdx.y == 1 ? Ok : Ov);
  const int h = blockIdx.x;
  const int t = threadIdx.x;
  const int ee = t & 63, r0 = t >> 6;
  for (int d0 = 0; d0 < 1024; d0 += 64) {
    __syncthreads();
    for (int dd = r0; dd < 64; dd += 4)
      tile[dd][ee] = W[(h * 1024 + d0 + dd) * 64 + ee];
    __syncthreads();
    const int d = t & 63, e0 = t >> 6;
    for (int e = e0; e < 64; e += 4)
      O[(h * 64 + e) * 1024 + d0 + d] = f2bf(tile[d][e]);
  }
}

// Wp [1024][1024] f32 -> Wpt [n][k] bf16 (transposed)
__global__ __launch_bounds__(256) void k_packp(const float* __restrict__ W,
                                               unsigned short* __restrict__ O) {
  __shared__ float tile[64][65];
  const int k0 = blockIdx.x * 64, n0 = blockIdx.y * 64;
  const int t = threadIdx.x;
  const int nn = t & 63, r0 = t >> 6;
  for (int kk = r0; kk < 64; kk += 4)
    tile[kk][nn] = W[(k0 + kk) * 1024 + n0 + nn];
  __syncthreads();
  const int kk = t & 63, e0 = t >> 6;
  for (int n2 = e0; n2 < 64; n2 += 4)
    O[(n0 + n2) * 1024 + k0 + kk] = f2bf(tile[kk][n2]);
}

// ---------------- GEMM: C[8192x1024] = A[8192x1024] * Bt[1024x1024]^T + bias ----------------
__global__ __launch_bounds__(256) void k_gemm(const unsigned short* __restrict__ A,
                                              const unsigned short* __restrict__ Bt,
                                              const float* __restrict__ bias,
                                              void* __restrict__ outp,
                                              int mode, float oscale) {
  __shared__ unsigned short As[4096];  // 128 rows x 32 k, swizzled (8 KB)
  __shared__ unsigned short Bs[4096];
  const int tid = threadIdx.x;
  const int l = tid & 63, w = tid >> 6;
  const int lrow = l & 15, lk = l >> 4;
  const int wr = (w >> 1) * 64, wc = (w & 1) * 64;
  const int brow = blockIdx.x * 128, bcol = blockIdx.y * 128;

  const int arow = tid >> 2;
  const int asrc = ((tid & 3) ^ ((arow >> 1) & 3)) * 8;
  const unsigned short* ag0 = A + (brow + arow) * 1024 + asrc;
  const unsigned short* ag1 = ag0 + 64 * 1024;
  const unsigned short* bg0 = Bt + (bcol + arow) * 1024 + asrc;
  const unsigned short* bg1 = bg0 + 64 * 1024;
  char* asb = (char*)As + w * 1024;
  char* bsb = (char*)Bs + w * 1024;

  int aoff[4], boff[4];
#pragma unroll
  for (int m = 0; m < 4; m++) {
    int row = wr + m * 16 + lrow;
    aoff[m] = row * 64 + ((lk ^ ((row >> 1) & 3)) << 4);
    int col = wc + m * 16 + lrow;
    boff[m] = col * 64 + ((lk ^ ((col >> 1) & 3)) << 4);
  }

  f32x4 acc[4][4];
#pragma unroll
  for (int n = 0; n < 4; n++) {
    float bv = bias[bcol + wc + n * 16 + lrow];
#pragma unroll
    for (int m = 0; m < 4; m++) acc[m][n] = (f32x4){bv, bv, bv, bv};
  }

  for (int kt = 0; kt < 32; kt++) {
    __syncthreads();
    gload16(ag0 + kt * 32, asb);
    gload16(ag1 + kt * 32, asb + 4096);
    gload16(bg0 + kt * 32, bsb);
    gload16(bg1 + kt * 32, bsb + 4096);
    __syncthreads();
    bf16x8 af[4], bfr[4];
#pragma unroll
    for (int m = 0; m < 4; m++) af[m] = *(const bf16x8*)((const char*)As + aoff[m]);
#pragma unroll
    for (int n = 0; n < 4; n++) bfr[n] = *(const bf16x8*)((const char*)Bs + boff[n]);
#pragma unroll
    for (int m = 0; m < 4; m++)
#pragma unroll
      for (int n = 0; n < 4; n++)
        acc[m][n] = mfma16(af[m], bfr[n], acc[m][n]);
  }

  if (mode == 0) {
    unsigned short* C = (unsigned short*)outp;
#pragma unroll
    for (int m = 0; m < 4; m++) {
      int r = brow + wr + m * 16 + 4 * lk;
#pragma unroll
      for (int n = 0; n < 4; n++) {
        int c = bcol + wc + n * 16 + lrow;
        unsigned short* p = C + ((r >> 10) * 16 + (c >> 6)) * 65536 + (r & 1023) * 64 + (c & 63);
#pragma unroll
        for (int j = 0; j < 4; j++) p[j * 64] = f2bf(acc[m][n][j] * oscale);
      }
    }
  } else if (mode == 2) {
    unsigned short* C = (unsigned short*)outp;
#pragma unroll
    for (int m = 0; m < 4; m++) {
      int r = brow + wr + m * 16 + 4 * lk;
#pragma unroll
      for (int n = 0; n < 4; n++) {
        int c = bcol + wc + n * 16 + lrow;
        u16x4 o;
#pragma unroll
        for (int j = 0; j < 4; j++) o[j] = f2bf(acc[m][n][j]);
        *(u16x4*)(C + ((r >> 10) * 16 + (c >> 6)) * 65536 + (c & 63) * 1024 + (r & 1023)) = o;
      }
    }
  } else {
    float* C = (float*)outp;
#pragma unroll
    for (int m = 0; m < 4; m++) {
      int r = brow + wr + m * 16 + 4 * lk;
#pragma unroll
      for (int n = 0; n < 4; n++) {
        int c = bcol + wc + n * 16 + lrow;
#pragma unroll
        for (int j = 0; j < 4; j++) C[(r + j) * 1024 + c] = acc[m][n][j];
      }
    }
  }
}

// ---------------- flash attention (round-1 orientation, 32 q per wave) ----------------
// Q [bh][1024][64] (prescaled by 0.125*log2e), K [bh][1024][64], Vt [bh][64][1024]
// -> Y [b*1024+x][h*64+e] bf16. Causal.
// Block = 128 q rows, 4 waves x 32 q (2 x 16-row fragments). KV tiles of 64.
// S = mfma(Qfrag, Kfrag): D row = q (lk*4+j), D col = z (zf*16+lrow). Round-1 validated.
__global__ __launch_bounds__(256) void k_attn(const unsigned short* __restrict__ Qh,
                                              const unsigned short* __restrict__ Kh,
                                              const unsigned short* __restrict__ Vth,
                                              unsigned short* __restrict__ Y) {
  __shared__ unsigned short Ks[4096];  // 64 z x 64 d, swizzled (8 KB)
  __shared__ unsigned short Vs[4096];  // 64 e x 64 z, swizzled (8 KB)
  __shared__ unsigned short Ps[8192];  // 4 waves x (32 q x 64 z), swizzled (16 KB)

  const int tid = threadIdx.x, l = tid & 63, w = tid >> 6;
  const int lrow = l & 15, lk = l >> 4;
  const int bh = blockIdx.y;
  const int qi = 7 - blockIdx.x;   // biggest blocks dispatched first
  const int q0b = qi * 128;
  const int qw = q0b + w * 32;     // wave's min q
  const int qmax = qw + 31;

  const unsigned short* Qb = Qh + bh * 65536;
  const unsigned short* Kb = Kh + bh * 65536;
  const unsigned short* Vb = Vth + bh * 65536;

  // Q fragments: lane holds Q[qw + qn*16 + lrow][kf*32 + lk*8 + 0..7]
  bf16x8 qf[2][2];
#pragma unroll
  for (int qn = 0; qn < 2; qn++) {
    const unsigned short* qp = Qb + (qw + qn * 16 + lrow) * 64 + lk * 8;
    qf[qn][0] = *(const bf16x8*)qp;
    qf[qn][1] = *(const bf16x8*)(qp + 32);
  }

  // ones B-fragment for lsum-via-MFMA (element-wise init)
  bf16x8 ones;
#pragma unroll
  for (int j = 0; j < 8; j++) ones[j] = (__bf16)1.0f;

  f32x4 m[2], lsum[2], yacc[2][4];
#pragma unroll
  for (int qn = 0; qn < 2; qn++) {
    m[qn] = (f32x4){MASKNEG, MASKNEG, MASKNEG, MASKNEG};
    lsum[qn] = (f32x4){0.f, 0.f, 0.f, 0.f};
#pragma unroll
    for (int ef = 0; ef < 4; ef++) yacc[qn][ef] = (f32x4){0.f, 0.f, 0.f, 0.f};
  }

  const int srow = tid >> 3;
  const int swz = ((tid & 7) ^ (srow & 7)) * 8;
  const unsigned short* kg0 = Kb + srow * 64 + swz;
  const unsigned short* kg1 = Kb + (srow + 32) * 64 + swz;
  const unsigned short* vg0 = Vb + srow * 1024 + swz;
  const unsigned short* vg1 = Vb + (srow + 32) * 1024 + swz;
  char* ksb = (char*)Ks + w * 1024;
  char* vsb = (char*)Vs + w * 1024;
  char* pw = (char*)Ps + w * 4096;   // 32 q-rows x 128 B

  const int nt = qi * 2 + 2;
  for (int t = 0; t < nt; t++) {
    const int z0 = t * 64;
    __syncthreads();
    gload16(kg0 + z0 * 64, ksb);
    gload16(kg1 + z0 * 64, ksb + 4096);
    gload16(vg0 + z0, vsb);
    gload16(vg1 + z0, vsb + 4096);
    __syncthreads();

    if (z0 > qmax) continue;  // tile fully masked for this wave (barriers matched)

    // S: lane holds S[q = qw + qn*16 + lk*4 + j][z = z0 + zf*16 + lrow]
    f32x4 s[2][4];
#pragma unroll
    for (int qn = 0; qn < 2; qn++)
#pragma unroll
      for (int zf = 0; zf < 4; zf++) s[qn][zf] = (f32x4){0.f, 0.f, 0.f, 0.f};
#pragma unroll
    for (int zf = 0; zf < 4; zf++) {
      int zr = zf * 16 + lrow;
#pragma unroll
      for (int kf = 0; kf < 2; kf++) {
        bf16x8 kfr = *(const bf16x8*)((const char*)Ks + zr * 128 + (((kf * 4 + lk) ^ (zr & 7)) << 4));
        s[0][zf] = mfma16(qf[0][kf], kfr, s[0][zf]);
        s[1][zf] = mfma16(qf[1][kf], kfr, s[1][zf]);
      }
    }

    if (z0 + 63 > qw) {  // diagonal overlap: mask z > q (finite sentinel)
#pragma unroll
      for (int qn = 0; qn < 2; qn++) {
        int qbase = qw + qn * 16 + 4 * lk;
#pragma unroll
        for (int zf = 0; zf < 4; zf++) {
          int zg = z0 + zf * 16 + lrow;
#pragma unroll
          for (int j = 0; j < 4; j++)
            if (zg > qbase + j) s[qn][zf][j] = MASKNEG;
        }
      }
    }

    // online softmax per (qn, j): row q = 4*lk + j lives across 16 lanes (lrow) x 4 zf
#pragma unroll
    for (int qn = 0; qn < 2; qn++) {
#pragma unroll
      for (int j = 0; j < 4; j++) {
        float rm = fmaxf(fmaxf(s[qn][0][j], s[qn][1][j]), fmaxf(s[qn][2][j], s[qn][3][j]));
        rm = fmaxf(rm, __shfl_xor(rm, 1));
        rm = fmaxf(rm, __shfl_xor(rm, 2));
        rm = fmaxf(rm, __shfl_xor(rm, 4));
        rm = fmaxf(rm, __shfl_xor(rm, 8));
        float mn = fmaxf(m[qn][j], rm);
        float a = __builtin_amdgcn_exp2f(m[qn][j] - mn);  // <=0 arg
        m[qn][j] = mn;
        lsum[qn][j] *= a;
#pragma unroll
        for (int ef = 0; ef < 4; ef++) yacc[qn][ef][j] *= a;
#pragma unroll
        for (int zf = 0; zf < 4; zf++)
          s[qn][zf][j] = __builtin_amdgcn_exp2f(s[qn][zf][j] - mn);  // <=0 arg
      }

      // P -> per-wave LDS (bf16, round-1 swizzle), row = qn*16 + 4*lk + j
#pragma unroll
      for (int zf = 0; zf < 4; zf++) {
        int zc = zf * 16 + lrow;
        int zp = zc >> 3;
#pragma unroll
        for (int j = 0; j < 4; j++) {
          int q = 4 * lk + j;
          *(unsigned short*)(pw + (qn * 16 + q) * 128 + ((zp ^ (q & 7)) << 4) + (zc & 7) * 2)
              = f2bf(s[qn][zf][j]);
        }
      }
    }

    // hard wall: DS writes complete, no reordering (TBAA guard for the u16/bf16x8 pun)
    asm volatile("s_waitcnt lgkmcnt(0)" ::: "memory");
    __builtin_amdgcn_sched_barrier(0);

    // read P as A-fragments: lane holds P[q = qn*16 + lrow][z = kf*32 + lk*8 + 0..7]
    bf16x8 pf[2][2];
#pragma unroll
    for (int qn = 0; qn < 2; qn++)
#pragma unroll
      for (int kf = 0; kf < 2; kf++)
        pf[qn][kf] = *(const bf16x8*)(pw + (qn * 16 + lrow) * 128 + (((kf * 4 + lk) ^ (lrow & 7)) << 4));

    // lsum += rowsum(P) via ones-MFMA (D-row = q matches yacc layout; cols uniform)
#pragma unroll
    for (int qn = 0; qn < 2; qn++)
#pragma unroll
      for (int kf = 0; kf < 2; kf++)
        lsum[qn] = mfma16(pf[qn][kf], ones, lsum[qn]);

    // Y += P V  (B-frag: V^T rows e from Vs)
#pragma unroll
    for (int ef = 0; ef < 4; ef++) {
      int er = ef * 16 + lrow;
#pragma unroll
      for (int kf = 0; kf < 2; kf++) {
        bf16x8 vf = *(const bf16x8*)((const char*)Vs + er * 128 + (((kf * 4 + lk) ^ (er & 7)) << 4));
        yacc[0][ef] = mfma16(pf[0][kf], vf, yacc[0][ef]);
        yacc[1][ef] = mfma16(pf[1][kf], vf, yacc[1][ef]);
      }
    }
  }

  // epilogue: Y[q][e] = yacc / lsum ; q = qw + qn*16 + lk*4 + j, e = ef*16 + lrow
  const int b = bh >> 4, h = bh & 15;
#pragma unroll
  for (int qn = 0; qn < 2; qn++) {
    f32x4 rinv;
#pragma unroll
    for (int j = 0; j < 4; j++) rinv[j] = 1.0f / lsum[qn][j];
#pragma unroll
    for (int ef = 0; ef < 4; ef++) {
      int col = h * 64 + ef * 16 + lrow;
#pragma unroll
      for (int j = 0; j < 4; j++) {
        int x = qw + qn * 16 + lk * 4 + j;
        Y[(b * 1024 + x) * 1024 + col] = f2bf(yacc[qn][ef][j] * rinv[j]);
      }
    }
  }
}

// ---------------- launch ----------------
extern "C" void kernel_launch(void* const* d_in, const int* in_sizes, int n_in,
                              void* d_out, int out_size, void* d_ws, size_t ws_size,
                              hipStream_t stream) {
  const float* x  = (const float*)d_in[0];
  const float* z  = (const float*)d_in[1];
  const float* Wq = (const float*)d_in[2];
  const float* bq = (const float*)d_in[3];
  const float* Wk = (const float*)d_in[4];
  const float* bk = (const float*)d_in[5];
  const float* Wv = (const float*)d_in[6];
  const float* bv = (const float*)d_in[7];
  const float* Wp = (const float*)d_in[8];
  const float* bp = (const float*)d_in[9];
  (void)in_sizes; (void)n_in; (void)out_size; (void)ws_size;

  char* ws = (char*)d_ws;
  unsigned short* Xb  = (unsigned short*)(ws + 0);         // 16 MB (re-used as Y)
  unsigned short* Zb  = (unsigned short*)(ws + 16777216);  // 16 MB
  unsigned short* Wqt = (unsigned short*)(ws + 33554432);  // 2 MB
  unsigned short* Wkt = (unsigned short*)(ws + 35651584);  // 2 MB
  unsigned short* Wvt = (unsigned short*)(ws + 37748736);  // 2 MB
  unsigned short* Wpt = (unsigned short*)(ws + 39845888);  // 2 MB
  unsigned short* Qp  = (unsigned short*)(ws + 41943040);  // 16 MB
  unsigned short* Kp  = (unsigned short*)(ws + 58720256);  // 16 MB
  unsigned short* Vtp = (unsigned short*)(ws + 75497472);  // 16 MB

  k_cvt<<<dim3(2048), dim3(256), 0, stream>>>(x, Xb, 1048576);
  k_cvt<<<dim3(2048), dim3(256), 0, stream>>>(z, Zb, 1048576);
  k_packw<<<dim3(16, 3), dim3(256), 0, stream>>>(Wq, Wk, Wv, Wqt, Wkt, Wvt);
  k_packp<<<dim3(16, 16), dim3(256), 0, stream>>>(Wp, Wpt);

  const float QSCALE = 0.125f * 1.4426950408889634f;  // 1/sqrt(64) * log2(e)
  k_gemm<<<dim3(64, 8), dim3(256), 0, stream>>>(Xb, Wqt, bq, Qp, 0, QSCALE);
  k_gemm<<<dim3(64, 8), dim3(256), 0, stream>>>(Zb, Wkt, bk, Kp, 0, 1.0f);
  k_gemm<<<dim3(64, 8), dim3(256), 0, stream>>>(Zb, Wvt, bv, Vtp, 2, 1.0f);

  k_attn<<<dim3(8, 128), dim3(256), 0, stream>>>(Qp, Kp, Vtp, Xb /*Y*/);

  k_gemm<<<dim3(64, 8), dim3(256), 0, stream>>>(Xb, Wpt, bp, d_out, 3, 1.0f);
}

// Round 5
// 234.941 us; speedup vs baseline: 1.1971x; 1.1481x over previous
//
#include <hip/hip_runtime.h>
#include <stdint.h>

// Pipeline: cvt x,z -> bf16; pack weights; fused QKV GEMM (bf16 MFMA);
// flash attention (causal, online softmax, work-balanced paired q-blocks);
// output GEMM -> f32.
// B=8 TX=TZ=1024 DX=DZ=1024 DATT=DMID=64 H=16 DOUT=1024.

typedef float    f32x4  __attribute__((ext_vector_type(4)));
typedef __bf16   bf16x8 __attribute__((ext_vector_type(8)));
typedef unsigned short u16x4 __attribute__((ext_vector_type(4)));
typedef unsigned short u16x8 __attribute__((ext_vector_type(8)));

#define MASKNEG (-3.0e38f)
#define QSCALE_F (0.125f * 1.4426950408889634f)

__device__ __forceinline__ unsigned short f2bf(float f) {
  unsigned int u = __float_as_uint(f);
  u += 0x7fffu + ((u >> 16) & 1u);   // RNE
  return (unsigned short)(u >> 16);
}

__device__ __forceinline__ void gload16(const void* g, void* s) {
  const __attribute__((address_space(1))) unsigned int* gp =
      (const __attribute__((address_space(1))) unsigned int*)(uintptr_t)g;
  __attribute__((address_space(3))) unsigned int* lp =
      (__attribute__((address_space(3))) unsigned int*)(unsigned int)(uintptr_t)s;
  __builtin_amdgcn_global_load_lds(gp, lp, 16, 0, 0);
}

__device__ __forceinline__ f32x4 mfma16(bf16x8 a, bf16x8 b, f32x4 c) {
  return __builtin_amdgcn_mfma_f32_16x16x32_bf16(a, b, c, 0, 0, 0);
}

// ---------------- prep kernels ----------------

__global__ __launch_bounds__(256) void k_cvt(const float* __restrict__ in,
                                             unsigned short* __restrict__ out, int n8) {
  int i = blockIdx.x * 256 + threadIdx.x;
  int stride = gridDim.x * 256;
  for (; i < n8; i += stride) {
    const f32x4* p = (const f32x4*)(in + (size_t)i * 8);
    f32x4 a = p[0], b = p[1];
    u16x8 o;
    o[0] = f2bf(a[0]); o[1] = f2bf(a[1]); o[2] = f2bf(a[2]); o[3] = f2bf(a[3]);
    o[4] = f2bf(b[0]); o[5] = f2bf(b[1]); o[6] = f2bf(b[2]); o[7] = f2bf(b[3]);
    *(u16x8*)(out + (size_t)i * 8) = o;
  }
}

// Wq/Wk/Wv [H][DX][64] f32 -> Wt [H*64+e][DX] bf16   (K-contiguous NT layout)
__global__ __launch_bounds__(256) void k_packw(const float* __restrict__ Wq,
                                               const float* __restrict__ Wk,
                                               const float* __restrict__ Wv,
                                               unsigned short* __restrict__ Oq,
                                               unsigned short* __restrict__ Ok,
                                               unsigned short* __restrict__ Ov) {
  __shared__ float tile[64][65];
  const float* W = blockIdx.y == 0 ? Wq : (blockIdx.y == 1 ? Wk : Wv);
  unsigned short* O = blockIdx.y == 0 ? Oq : (blockIdx.y == 1 ? Ok : Ov);
  const int h = blockIdx.x;
  const int t = threadIdx.x;
  const int ee = t & 63, r0 = t >> 6;
  for (int d0 = 0; d0 < 1024; d0 += 64) {
    __syncthreads();
    for (int dd = r0; dd < 64; dd += 4)
      tile[dd][ee] = W[(h * 1024 + d0 + dd) * 64 + ee];
    __syncthreads();
    const int d = t & 63, e0 = t >> 6;
    for (int e = e0; e < 64; e += 4)
      O[(h * 64 + e) * 1024 + d0 + d] = f2bf(tile[d][e]);
  }
}

// Wp [1024][1024] f32 -> Wpt [n][k] bf16 (transposed)
__global__ __launch_bounds__(256) void k_packp(const float* __restrict__ W,
                                               unsigned short* __restrict__ O) {
  __shared__ float tile[64][65];
  const int k0 = blockIdx.x * 64, n0 = blockIdx.y * 64;
  const int t = threadIdx.x;
  const int nn = t & 63, r0 = t >> 6;
  for (int kk = r0; kk < 64; kk += 4)
    tile[kk][nn] = W[(k0 + kk) * 1024 + n0 + nn];
  __syncthreads();
  const int kk = t & 63, e0 = t >> 6;
  for (int n2 = e0; n2 < 64; n2 += 4)
    O[(n0 + n2) * 1024 + k0 + kk] = f2bf(tile[kk][n2]);
}

// ---------------- GEMM body: C[128x128 tile] = A * Bt^T + bias ----------------
// mode 0: bf16 out to [bh][x][64] (Q/K), scaled by oscale
// mode 2: bf16 out to [bh][e][z]  (V transposed)
// mode 3: f32 out, row-major (final projection)
__device__ __forceinline__ void gemm_body(const unsigned short* __restrict__ A,
                                          const unsigned short* __restrict__ Bt,
                                          const float* __restrict__ bias,
                                          void* __restrict__ outp,
                                          int mode, float oscale,
                                          int brow, int bcol,
                                          unsigned short* As, unsigned short* Bs) {
  const int tid = threadIdx.x;
  const int l = tid & 63, w = tid >> 6;
  const int lrow = l & 15, lk = l >> 4;
  const int wr = (w >> 1) * 64, wc = (w & 1) * 64;

  const int arow = tid >> 2;
  const int asrc = ((tid & 3) ^ ((arow >> 1) & 3)) * 8;
  const unsigned short* ag0 = A + (brow + arow) * 1024 + asrc;
  const unsigned short* ag1 = ag0 + 64 * 1024;
  const unsigned short* bg0 = Bt + (bcol + arow) * 1024 + asrc;
  const unsigned short* bg1 = bg0 + 64 * 1024;
  char* asb = (char*)As + w * 1024;
  char* bsb = (char*)Bs + w * 1024;

  int aoff[4], boff[4];
#pragma unroll
  for (int m = 0; m < 4; m++) {
    int row = wr + m * 16 + lrow;
    aoff[m] = row * 64 + ((lk ^ ((row >> 1) & 3)) << 4);
    int col = wc + m * 16 + lrow;
    boff[m] = col * 64 + ((lk ^ ((col >> 1) & 3)) << 4);
  }

  f32x4 acc[4][4];
#pragma unroll
  for (int n = 0; n < 4; n++) {
    float bv = bias[bcol + wc + n * 16 + lrow];
#pragma unroll
    for (int m = 0; m < 4; m++) acc[m][n] = (f32x4){bv, bv, bv, bv};
  }

  for (int kt = 0; kt < 32; kt++) {
    __syncthreads();
    gload16(ag0 + kt * 32, asb);
    gload16(ag1 + kt * 32, asb + 4096);
    gload16(bg0 + kt * 32, bsb);
    gload16(bg1 + kt * 32, bsb + 4096);
    __syncthreads();
    bf16x8 af[4], bfr[4];
#pragma unroll
    for (int m = 0; m < 4; m++) af[m] = *(const bf16x8*)((const char*)As + aoff[m]);
#pragma unroll
    for (int n = 0; n < 4; n++) bfr[n] = *(const bf16x8*)((const char*)Bs + boff[n]);
#pragma unroll
    for (int m = 0; m < 4; m++)
#pragma unroll
      for (int n = 0; n < 4; n++)
        acc[m][n] = mfma16(af[m], bfr[n], acc[m][n]);
  }

  if (mode == 0) {
    unsigned short* C = (unsigned short*)outp;
#pragma unroll
    for (int m = 0; m < 4; m++) {
      int r = brow + wr + m * 16 + 4 * lk;
#pragma unroll
      for (int n = 0; n < 4; n++) {
        int c = bcol + wc + n * 16 + lrow;
        unsigned short* p = C + ((r >> 10) * 16 + (c >> 6)) * 65536 + (r & 1023) * 64 + (c & 63);
#pragma unroll
        for (int j = 0; j < 4; j++) p[j * 64] = f2bf(acc[m][n][j] * oscale);
      }
    }
  } else if (mode == 2) {
    unsigned short* C = (unsigned short*)outp;
#pragma unroll
    for (int m = 0; m < 4; m++) {
      int r = brow + wr + m * 16 + 4 * lk;
#pragma unroll
      for (int n = 0; n < 4; n++) {
        int c = bcol + wc + n * 16 + lrow;
        u16x4 o;
#pragma unroll
        for (int j = 0; j < 4; j++) o[j] = f2bf(acc[m][n][j]);
        *(u16x4*)(C + ((r >> 10) * 16 + (c >> 6)) * 65536 + (c & 63) * 1024 + (r & 1023)) = o;
      }
    }
  } else {
    float* C = (float*)outp;
#pragma unroll
    for (int m = 0; m < 4; m++) {
      int r = brow + wr + m * 16 + 4 * lk;
#pragma unroll
      for (int n = 0; n < 4; n++) {
        int c = bcol + wc + n * 16 + lrow;
#pragma unroll
        for (int j = 0; j < 4; j++) C[(r + j) * 1024 + c] = acc[m][n][j];
      }
    }
  }
}

// fused QKV: grid (64, 24); y>>3 = segment (0=Q,1=K,2=V), y&7 = col tile
__global__ __launch_bounds__(256) void k_gemm_qkv(const unsigned short* __restrict__ Xb,
                                                  const unsigned short* __restrict__ Zb,
                                                  const unsigned short* __restrict__ Wqkv,
                                                  const float* __restrict__ bq,
                                                  const float* __restrict__ bk,
                                                  const float* __restrict__ bv,
                                                  unsigned short* __restrict__ Qp,
                                                  unsigned short* __restrict__ Kp,
                                                  unsigned short* __restrict__ Vtp) {
  __shared__ unsigned short As[4096];
  __shared__ unsigned short Bs[4096];
  const int brow = blockIdx.x * 128;
  const int cg = blockIdx.y;
  const int seg = cg >> 3;
  const int bcol = (cg & 7) * 128;
  const unsigned short* A = (seg == 0) ? Xb : Zb;
  const unsigned short* Bt = Wqkv + (size_t)seg * 1048576;
  const float* bias = (seg == 0) ? bq : (seg == 1 ? bk : bv);
  void* outp = (seg == 0) ? (void*)Qp : (seg == 1 ? (void*)Kp : (void*)Vtp);
  const int mode = (seg == 2) ? 2 : 0;
  const float oscale = (seg == 0) ? QSCALE_F : 1.0f;
  gemm_body(A, Bt, bias, outp, mode, oscale, brow, bcol, As, Bs);
}

// final projection: C = Y * Wpt^T + bp (f32 out)
__global__ __launch_bounds__(256) void k_gemm(const unsigned short* __restrict__ A,
                                              const unsigned short* __restrict__ Bt,
                                              const float* __restrict__ bias,
                                              void* __restrict__ outp,
                                              int mode, float oscale) {
  __shared__ unsigned short As[4096];
  __shared__ unsigned short Bs[4096];
  gemm_body(A, Bt, bias, outp, mode, oscale, blockIdx.x * 128, blockIdx.y * 128, As, Bs);
}

// ---------------- flash attention (round-1 orientation, paired q-blocks) ----------------
// Q [bh][1024][64] (prescaled by 0.125*log2e), K [bh][1024][64], Vt [bh][64][1024]
// -> Y [b*1024+x][h*64+e] bf16. Causal.
// Block handles q-blocks qi=7-p and qi=p (constant 18 KV-tiles total -> balanced grid).
// Within a q-block: 4 waves x 32 q (2 x 16-row fragments). KV tiles of 64.
// S = mfma(Qfrag, Kfrag): D row = q (lk*4+j), D col = z (zf*16+lrow). Round-1 validated.
__global__ __launch_bounds__(256) void k_attn(const unsigned short* __restrict__ Qh,
                                              const unsigned short* __restrict__ Kh,
                                              const unsigned short* __restrict__ Vth,
                                              unsigned short* __restrict__ Y) {
  __shared__ unsigned short Ks[4096];  // 64 z x 64 d, swizzled (8 KB)
  __shared__ unsigned short Vs[4096];  // 64 e x 64 z, swizzled (8 KB)
  __shared__ unsigned short Ps[8192];  // 4 waves x (32 q x 64 z), swizzled (16 KB)

  const int tid = threadIdx.x, l = tid & 63, w = tid >> 6;
  const int lrow = l & 15, lk = l >> 4;
  const int bh = blockIdx.y;
  const int pp = blockIdx.x;       // 0..3 -> handles qi = 7-pp then qi = pp

  const unsigned short* Qb = Qh + bh * 65536;
  const unsigned short* Kb = Kh + bh * 65536;
  const unsigned short* Vb = Vth + bh * 65536;

  // ones B-fragment for lsum-via-MFMA (element-wise init)
  bf16x8 ones;
#pragma unroll
  for (int j = 0; j < 8; j++) ones[j] = (__bf16)1.0f;

  const int srow = tid >> 3;
  const int swz = ((tid & 7) ^ (srow & 7)) * 8;
  const unsigned short* kg0 = Kb + srow * 64 + swz;
  const unsigned short* kg1 = Kb + (srow + 32) * 64 + swz;
  const unsigned short* vg0 = Vb + srow * 1024 + swz;
  const unsigned short* vg1 = Vb + (srow + 32) * 1024 + swz;
  char* ksb = (char*)Ks + w * 1024;
  char* vsb = (char*)Vs + w * 1024;
  char* pw = (char*)Ps + w * 4096;   // 32 q-rows x 128 B

  const int b = bh >> 4, h = bh & 15;

#pragma unroll 1
  for (int half = 0; half < 2; half++) {
    const int qi = half == 0 ? (7 - pp) : pp;
    const int qw = qi * 128 + w * 32;   // wave's min q
    const int qmax = qw + 31;

    // Q fragments: lane holds Q[qw + qn*16 + lrow][kf*32 + lk*8 + 0..7]
    bf16x8 qf[2][2];
#pragma unroll
    for (int qn = 0; qn < 2; qn++) {
      const unsigned short* qp = Qb + (qw + qn * 16 + lrow) * 64 + lk * 8;
      qf[qn][0] = *(const bf16x8*)qp;
      qf[qn][1] = *(const bf16x8*)(qp + 32);
    }

    f32x4 m[2], lsum[2], yacc[2][4];
#pragma unroll
    for (int qn = 0; qn < 2; qn++) {
      m[qn] = (f32x4){MASKNEG, MASKNEG, MASKNEG, MASKNEG};
      lsum[qn] = (f32x4){0.f, 0.f, 0.f, 0.f};
#pragma unroll
      for (int ef = 0; ef < 4; ef++) yacc[qn][ef] = (f32x4){0.f, 0.f, 0.f, 0.f};
    }

    const int nt = qi * 2 + 2;
#pragma unroll 1
    for (int t = 0; t < nt; t++) {
      const int z0 = t * 64;
      __syncthreads();
      gload16(kg0 + z0 * 64, ksb);
      gload16(kg1 + z0 * 64, ksb + 4096);
      gload16(vg0 + z0, vsb);
      gload16(vg1 + z0, vsb + 4096);
      __syncthreads();

      if (z0 > qmax) continue;  // tile fully masked for this wave (barriers matched)

      // S: lane holds S[q = qw + qn*16 + lk*4 + j][z = z0 + zf*16 + lrow]
      f32x4 s[2][4];
#pragma unroll
      for (int qn = 0; qn < 2; qn++)
#pragma unroll
        for (int zf = 0; zf < 4; zf++) s[qn][zf] = (f32x4){0.f, 0.f, 0.f, 0.f};
#pragma unroll
      for (int zf = 0; zf < 4; zf++) {
        int zr = zf * 16 + lrow;
#pragma unroll
        for (int kf = 0; kf < 2; kf++) {
          bf16x8 kfr = *(const bf16x8*)((const char*)Ks + zr * 128 + (((kf * 4 + lk) ^ (zr & 7)) << 4));
          s[0][zf] = mfma16(qf[0][kf], kfr, s[0][zf]);
          s[1][zf] = mfma16(qf[1][kf], kfr, s[1][zf]);
        }
      }

      if (z0 + 63 > qw) {  // diagonal overlap: mask z > q (finite sentinel)
#pragma unroll
        for (int qn = 0; qn < 2; qn++) {
          int qbase = qw + qn * 16 + 4 * lk;
#pragma unroll
          for (int zf = 0; zf < 4; zf++) {
            int zg = z0 + zf * 16 + lrow;
#pragma unroll
            for (int j = 0; j < 4; j++)
              if (zg > qbase + j) s[qn][zf][j] = MASKNEG;
          }
        }
      }

      // online softmax per (qn, j): row q = 4*lk + j lives across 16 lanes (lrow) x 4 zf
#pragma unroll
      for (int qn = 0; qn < 2; qn++) {
#pragma unroll
        for (int j = 0; j < 4; j++) {
          float rm = fmaxf(fmaxf(s[qn][0][j], s[qn][1][j]), fmaxf(s[qn][2][j], s[qn][3][j]));
          rm = fmaxf(rm, __shfl_xor(rm, 1));
          rm = fmaxf(rm, __shfl_xor(rm, 2));
          rm = fmaxf(rm, __shfl_xor(rm, 4));
          rm = fmaxf(rm, __shfl_xor(rm, 8));
          float mn = fmaxf(m[qn][j], rm);
          float a = __builtin_amdgcn_exp2f(m[qn][j] - mn);  // <=0 arg
          m[qn][j] = mn;
          lsum[qn][j] *= a;
#pragma unroll
          for (int ef = 0; ef < 4; ef++) yacc[qn][ef][j] *= a;
#pragma unroll
          for (int zf = 0; zf < 4; zf++)
            s[qn][zf][j] = __builtin_amdgcn_exp2f(s[qn][zf][j] - mn);  // <=0 arg
        }

        // P -> per-wave LDS (bf16, round-1 swizzle), row = qn*16 + 4*lk + j
#pragma unroll
        for (int zf = 0; zf < 4; zf++) {
          int zc = zf * 16 + lrow;
          int zp = zc >> 3;
#pragma unroll
          for (int j = 0; j < 4; j++) {
            int q = 4 * lk + j;
            *(unsigned short*)(pw + (qn * 16 + q) * 128 + ((zp ^ (q & 7)) << 4) + (zc & 7) * 2)
                = f2bf(s[qn][zf][j]);
          }
        }
      }

      // hard wall: DS writes complete, no reordering (TBAA guard for the u16/bf16x8 pun)
      asm volatile("s_waitcnt lgkmcnt(0)" ::: "memory");
      __builtin_amdgcn_sched_barrier(0);

      // read P as A-fragments: lane holds P[q = qn*16 + lrow][z = kf*32 + lk*8 + 0..7]
      bf16x8 pf[2][2];
#pragma unroll
      for (int qn = 0; qn < 2; qn++)
#pragma unroll
        for (int kf = 0; kf < 2; kf++)
          pf[qn][kf] = *(const bf16x8*)(pw + (qn * 16 + lrow) * 128 + (((kf * 4 + lk) ^ (lrow & 7)) << 4));

      // lsum += rowsum(P) via ones-MFMA (D-row = q matches yacc layout; cols uniform)
#pragma unroll
      for (int qn = 0; qn < 2; qn++)
#pragma unroll
        for (int kf = 0; kf < 2; kf++)
          lsum[qn] = mfma16(pf[qn][kf], ones, lsum[qn]);

      // Y += P V  (B-frag: V^T rows e from Vs)
#pragma unroll
      for (int ef = 0; ef < 4; ef++) {
        int er = ef * 16 + lrow;
#pragma unroll
        for (int kf = 0; kf < 2; kf++) {
          bf16x8 vf = *(const bf16x8*)((const char*)Vs + er * 128 + (((kf * 4 + lk) ^ (er & 7)) << 4));
          yacc[0][ef] = mfma16(pf[0][kf], vf, yacc[0][ef]);
          yacc[1][ef] = mfma16(pf[1][kf], vf, yacc[1][ef]);
        }
      }
    }

    // epilogue: Y[q][e] = yacc / lsum ; q = qw + qn*16 + lk*4 + j, e = ef*16 + lrow
#pragma unroll
    for (int qn = 0; qn < 2; qn++) {
      f32x4 rinv;
#pragma unroll
      for (int j = 0; j < 4; j++) rinv[j] = 1.0f / lsum[qn][j];
#pragma unroll
      for (int ef = 0; ef < 4; ef++) {
        int col = h * 64 + ef * 16 + lrow;
#pragma unroll
        for (int j = 0; j < 4; j++) {
          int x = qw + qn * 16 + lk * 4 + j;
          Y[(b * 1024 + x) * 1024 + col] = f2bf(yacc[qn][ef][j] * rinv[j]);
        }
      }
    }
  }
}

// ---------------- launch ----------------
extern "C" void kernel_launch(void* const* d_in, const int* in_sizes, int n_in,
                              void* d_out, int out_size, void* d_ws, size_t ws_size,
                              hipStream_t stream) {
  const float* x  = (const float*)d_in[0];
  const float* z  = (const float*)d_in[1];
  const float* Wq = (const float*)d_in[2];
  const float* bq = (const float*)d_in[3];
  const float* Wk = (const float*)d_in[4];
  const float* bk = (const float*)d_in[5];
  const float* Wv = (const float*)d_in[6];
  const float* bv = (const float*)d_in[7];
  const float* Wp = (const float*)d_in[8];
  const float* bp = (const float*)d_in[9];
  (void)in_sizes; (void)n_in; (void)out_size; (void)ws_size;

  char* ws = (char*)d_ws;
  unsigned short* Xb  = (unsigned short*)(ws + 0);         // 16 MB (re-used as Y)
  unsigned short* Zb  = (unsigned short*)(ws + 16777216);  // 16 MB
  unsigned short* Wqt = (unsigned short*)(ws + 33554432);  // 2 MB  -- Wqt/Wkt/Wvt contiguous = Wqkv
  unsigned short* Wkt = (unsigned short*)(ws + 35651584);  // 2 MB
  unsigned short* Wvt = (unsigned short*)(ws + 37748736);  // 2 MB
  unsigned short* Wpt = (unsigned short*)(ws + 39845888);  // 2 MB
  unsigned short* Qp  = (unsigned short*)(ws + 41943040);  // 16 MB
  unsigned short* Kp  = (unsigned short*)(ws + 58720256);  // 16 MB
  unsigned short* Vtp = (unsigned short*)(ws + 75497472);  // 16 MB

  k_cvt<<<dim3(2048), dim3(256), 0, stream>>>(x, Xb, 1048576);
  k_cvt<<<dim3(2048), dim3(256), 0, stream>>>(z, Zb, 1048576);
  k_packw<<<dim3(16, 3), dim3(256), 0, stream>>>(Wq, Wk, Wv, Wqt, Wkt, Wvt);
  k_packp<<<dim3(16, 16), dim3(256), 0, stream>>>(Wp, Wpt);

  k_gemm_qkv<<<dim3(64, 24), dim3(256), 0, stream>>>(Xb, Zb, Wqt, bq, bk, bv, Qp, Kp, Vtp);

  k_attn<<<dim3(4, 128), dim3(256), 0, stream>>>(Qp, Kp, Vtp, Xb /*Y*/);

  k_gemm<<<dim3(64, 8), dim3(256), 0, stream>>>(Xb, Wpt, bp, d_out, 3, 1.0f);
}

// Round 6
// 220.578 us; speedup vs baseline: 1.2750x; 1.0651x over previous
//
#include <hip/hip_runtime.h>
#include <stdint.h>

// Pipeline: cvt x,z -> bf16; pack weights; fused QKV GEMM (bf16 MFMA, 2-phase dbuf);
// flash attention (causal, online softmax, paired q-blocks, 2-phase dbuf staging);
// output GEMM -> f32.
// B=8 TX=TZ=1024 DX=DZ=1024 DATT=DMID=64 H=16 DOUT=1024.

typedef float    f32x4  __attribute__((ext_vector_type(4)));
typedef __bf16   bf16x8 __attribute__((ext_vector_type(8)));
typedef unsigned short u16x4 __attribute__((ext_vector_type(4)));
typedef unsigned short u16x8 __attribute__((ext_vector_type(8)));

#define MASKNEG (-3.0e38f)
#define QSCALE_F (0.125f * 1.4426950408889634f)

__device__ __forceinline__ unsigned short f2bf(float f) {
  unsigned int u = __float_as_uint(f);
  u += 0x7fffu + ((u >> 16) & 1u);   // RNE
  return (unsigned short)(u >> 16);
}

__device__ __forceinline__ void gload16(const void* g, void* s) {
  const __attribute__((address_space(1))) unsigned int* gp =
      (const __attribute__((address_space(1))) unsigned int*)(uintptr_t)g;
  __attribute__((address_space(3))) unsigned int* lp =
      (__attribute__((address_space(3))) unsigned int*)(unsigned int)(uintptr_t)s;
  __builtin_amdgcn_global_load_lds(gp, lp, 16, 0, 0);
}

__device__ __forceinline__ f32x4 mfma16(bf16x8 a, bf16x8 b, f32x4 c) {
  return __builtin_amdgcn_mfma_f32_16x16x32_bf16(a, b, c, 0, 0, 0);
}

// ---------------- prep kernels ----------------

__global__ __launch_bounds__(256) void k_cvt(const float* __restrict__ in,
                                             unsigned short* __restrict__ out, int n8) {
  int i = blockIdx.x * 256 + threadIdx.x;
  int stride = gridDim.x * 256;
  for (; i < n8; i += stride) {
    const f32x4* p = (const f32x4*)(in + (size_t)i * 8);
    f32x4 a = p[0], b = p[1];
    u16x8 o;
    o[0] = f2bf(a[0]); o[1] = f2bf(a[1]); o[2] = f2bf(a[2]); o[3] = f2bf(a[3]);
    o[4] = f2bf(b[0]); o[5] = f2bf(b[1]); o[6] = f2bf(b[2]); o[7] = f2bf(b[3]);
    *(u16x8*)(out + (size_t)i * 8) = o;
  }
}

// Wq/Wk/Wv [H][DX][64] f32 -> Wt [H*64+e][DX] bf16   (K-contiguous NT layout)
__global__ __launch_bounds__(256) void k_packw(const float* __restrict__ Wq,
                                               const float* __restrict__ Wk,
                                               const float* __restrict__ Wv,
                                               unsigned short* __restrict__ Oq,
                                               unsigned short* __restrict__ Ok,
                                               unsigned short* __restrict__ Ov) {
  __shared__ float tile[64][65];
  const float* W = blockIdx.y == 0 ? Wq : (blockIdx.y == 1 ? Wk : Wv);
  unsigned short* O = blockIdx.y == 0 ? Oq : (blockIdx.y == 1 ? Ok : Ov);
  const int h = blockIdx.x;
  const int t = threadIdx.x;
  const int ee = t & 63, r0 = t >> 6;
  for (int d0 = 0; d0 < 1024; d0 += 64) {
    __syncthreads();
    for (int dd = r0; dd < 64; dd += 4)
      tile[dd][ee] = W[(h * 1024 + d0 + dd) * 64 + ee];
    __syncthreads();
    const int d = t & 63, e0 = t >> 6;
    for (int e = e0; e < 64; e += 4)
      O[(h * 64 + e) * 1024 + d0 + d] = f2bf(tile[d][e]);
  }
}

// Wp [1024][1024] f32 -> Wpt [n][k] bf16 (transposed)
__global__ __launch_bounds__(256) void k_packp(const float* __restrict__ W,
                                               unsigned short* __restrict__ O) {
  __shared__ float tile[64][65];
  const int k0 = blockIdx.x * 64, n0 = blockIdx.y * 64;
  const int t = threadIdx.x;
  const int nn = t & 63, r0 = t >> 6;
  for (int kk = r0; kk < 64; kk += 4)
    tile[kk][nn] = W[(k0 + kk) * 1024 + n0 + nn];
  __syncthreads();
  const int kk = t & 63, e0 = t >> 6;
  for (int n2 = e0; n2 < 64; n2 += 4)
    O[(n0 + n2) * 1024 + k0 + kk] = f2bf(tile[kk][n2]);
}

// ---------------- GEMM body: C[128x128 tile] = A * Bt^T + bias ----------------
// 2-phase double-buffered: stage kt+1 while computing kt; ONE barrier per K-step.
// As/Bs: 8192 shorts each (2 buffers x 4096).
// mode 0: bf16 out to [bh][x][64] (Q/K), scaled by oscale
// mode 2: bf16 out to [bh][e][z]  (V transposed)
// mode 3: f32 out, row-major (final projection)
__device__ __forceinline__ void gemm_body(const unsigned short* __restrict__ A,
                                          const unsigned short* __restrict__ Bt,
                                          const float* __restrict__ bias,
                                          void* __restrict__ outp,
                                          int mode, float oscale,
                                          int brow, int bcol,
                                          unsigned short* As, unsigned short* Bs) {
  const int tid = threadIdx.x;
  const int l = tid & 63, w = tid >> 6;
  const int lrow = l & 15, lk = l >> 4;
  const int wr = (w >> 1) * 64, wc = (w & 1) * 64;

  const int arow = tid >> 2;
  const int asrc = ((tid & 3) ^ ((arow >> 1) & 3)) * 8;
  const unsigned short* ag0 = A + (brow + arow) * 1024 + asrc;
  const unsigned short* ag1 = ag0 + 64 * 1024;
  const unsigned short* bg0 = Bt + (bcol + arow) * 1024 + asrc;
  const unsigned short* bg1 = bg0 + 64 * 1024;

  int aoff[4], boff[4];
#pragma unroll
  for (int m = 0; m < 4; m++) {
    int row = wr + m * 16 + lrow;
    aoff[m] = row * 64 + ((lk ^ ((row >> 1) & 3)) << 4);
    int col = wc + m * 16 + lrow;
    boff[m] = col * 64 + ((lk ^ ((col >> 1) & 3)) << 4);
  }

  f32x4 acc[4][4];
#pragma unroll
  for (int n = 0; n < 4; n++) {
    float bv = bias[bcol + wc + n * 16 + lrow];
#pragma unroll
    for (int m = 0; m < 4; m++) acc[m][n] = (f32x4){bv, bv, bv, bv};
  }

  // prologue: stage kt=0 into buffer 0
  {
    char* asb = (char*)As + w * 1024;
    char* bsb = (char*)Bs + w * 1024;
    gload16(ag0, asb);
    gload16(ag1, asb + 4096);
    gload16(bg0, bsb);
    gload16(bg1, bsb + 4096);
  }
  __syncthreads();

#pragma unroll 2
  for (int kt = 0; kt < 32; kt++) {
    const int cur = kt & 1;
    if (kt < 31) {  // stage next tile into the other buffer (overlaps MFMA below)
      char* asb = (char*)As + (cur ^ 1) * 8192 + w * 1024;
      char* bsb = (char*)Bs + (cur ^ 1) * 8192 + w * 1024;
      gload16(ag0 + (kt + 1) * 32, asb);
      gload16(ag1 + (kt + 1) * 32, asb + 4096);
      gload16(bg0 + (kt + 1) * 32, bsb);
      gload16(bg1 + (kt + 1) * 32, bsb + 4096);
    }
    const char* ab = (const char*)As + cur * 8192;
    const char* bb = (const char*)Bs + cur * 8192;
    bf16x8 af[4], bfr[4];
#pragma unroll
    for (int m = 0; m < 4; m++) af[m] = *(const bf16x8*)(ab + aoff[m]);
#pragma unroll
    for (int n = 0; n < 4; n++) bfr[n] = *(const bf16x8*)(bb + boff[n]);
#pragma unroll
    for (int m = 0; m < 4; m++)
#pragma unroll
      for (int n = 0; n < 4; n++)
        acc[m][n] = mfma16(af[m], bfr[n], acc[m][n]);
    __syncthreads();  // drains vmcnt(0): next tile staged; all reads of cur done
  }

  if (mode == 0) {
    unsigned short* C = (unsigned short*)outp;
#pragma unroll
    for (int m = 0; m < 4; m++) {
      int r = brow + wr + m * 16 + 4 * lk;
#pragma unroll
      for (int n = 0; n < 4; n++) {
        int c = bcol + wc + n * 16 + lrow;
        unsigned short* p = C + ((r >> 10) * 16 + (c >> 6)) * 65536 + (r & 1023) * 64 + (c & 63);
#pragma unroll
        for (int j = 0; j < 4; j++) p[j * 64] = f2bf(acc[m][n][j] * oscale);
      }
    }
  } else if (mode == 2) {
    unsigned short* C = (unsigned short*)outp;
#pragma unroll
    for (int m = 0; m < 4; m++) {
      int r = brow + wr + m * 16 + 4 * lk;
#pragma unroll
      for (int n = 0; n < 4; n++) {
        int c = bcol + wc + n * 16 + lrow;
        u16x4 o;
#pragma unroll
        for (int j = 0; j < 4; j++) o[j] = f2bf(acc[m][n][j]);
        *(u16x4*)(C + ((r >> 10) * 16 + (c >> 6)) * 65536 + (c & 63) * 1024 + (r & 1023)) = o;
      }
    }
  } else {
    float* C = (float*)outp;
#pragma unroll
    for (int m = 0; m < 4; m++) {
      int r = brow + wr + m * 16 + 4 * lk;
#pragma unroll
      for (int n = 0; n < 4; n++) {
        int c = bcol + wc + n * 16 + lrow;
#pragma unroll
        for (int j = 0; j < 4; j++) C[(r + j) * 1024 + c] = acc[m][n][j];
      }
    }
  }
}

// fused QKV: grid (64, 24); y>>3 = segment (0=Q,1=K,2=V), y&7 = col tile
__global__ __launch_bounds__(256) void k_gemm_qkv(const unsigned short* __restrict__ Xb,
                                                  const unsigned short* __restrict__ Zb,
                                                  const unsigned short* __restrict__ Wqkv,
                                                  const float* __restrict__ bq,
                                                  const float* __restrict__ bk,
                                                  const float* __restrict__ bv,
                                                  unsigned short* __restrict__ Qp,
                                                  unsigned short* __restrict__ Kp,
                                                  unsigned short* __restrict__ Vtp) {
  __shared__ unsigned short As[8192];
  __shared__ unsigned short Bs[8192];
  const int brow = blockIdx.x * 128;
  const int cg = blockIdx.y;
  const int seg = cg >> 3;
  const int bcol = (cg & 7) * 128;
  const unsigned short* A = (seg == 0) ? Xb : Zb;
  const unsigned short* Bt = Wqkv + (size_t)seg * 1048576;
  const float* bias = (seg == 0) ? bq : (seg == 1 ? bk : bv);
  void* outp = (seg == 0) ? (void*)Qp : (seg == 1 ? (void*)Kp : (void*)Vtp);
  const int mode = (seg == 2) ? 2 : 0;
  const float oscale = (seg == 0) ? QSCALE_F : 1.0f;
  gemm_body(A, Bt, bias, outp, mode, oscale, brow, bcol, As, Bs);
}

// final projection: C = Y * Wpt^T + bp (f32 out)
__global__ __launch_bounds__(256) void k_gemm(const unsigned short* __restrict__ A,
                                              const unsigned short* __restrict__ Bt,
                                              const float* __restrict__ bias,
                                              void* __restrict__ outp,
                                              int mode, float oscale) {
  __shared__ unsigned short As[8192];
  __shared__ unsigned short Bs[8192];
  gemm_body(A, Bt, bias, outp, mode, oscale, blockIdx.x * 128, blockIdx.y * 128, As, Bs);
}

// ---------------- flash attention (round-1 orientation, paired q-blocks, 2-phase) ----------------
// Q [bh][1024][64] (prescaled by 0.125*log2e), K [bh][1024][64], Vt [bh][64][1024]
// -> Y [b*1024+x][h*64+e] bf16. Causal.
// Block handles q-blocks qi=7-p and qi=p (constant 18 KV-tiles -> balanced grid).
// Within a q-block: 4 waves x 32 q (2 x 16-row fragments). KV tiles of 64, double-buffered.
// S = mfma(Qfrag, Kfrag): D row = q (lk*4+j), D col = z (zf*16+lrow). Round-1 validated.
__global__ __launch_bounds__(256) void k_attn(const unsigned short* __restrict__ Qh,
                                              const unsigned short* __restrict__ Kh,
                                              const unsigned short* __restrict__ Vth,
                                              unsigned short* __restrict__ Y) {
  __shared__ unsigned short Ks[8192];  // 2 x (64 z x 64 d), swizzled (16 KB)
  __shared__ unsigned short Vs[8192];  // 2 x (64 e x 64 z), swizzled (16 KB)
  __shared__ unsigned short Ps[8192];  // 4 waves x (32 q x 64 z), swizzled (16 KB)

  const int tid = threadIdx.x, l = tid & 63, w = tid >> 6;
  const int lrow = l & 15, lk = l >> 4;
  const int bh = blockIdx.y;
  const int pp = blockIdx.x;       // 0..3 -> handles qi = 7-pp then qi = pp

  const unsigned short* Qb = Qh + bh * 65536;
  const unsigned short* Kb = Kh + bh * 65536;
  const unsigned short* Vb = Vth + bh * 65536;

  // ones B-fragment for lsum-via-MFMA (element-wise init)
  bf16x8 ones;
#pragma unroll
  for (int j = 0; j < 8; j++) ones[j] = (__bf16)1.0f;

  const int srow = tid >> 3;
  const int swz = ((tid & 7) ^ (srow & 7)) * 8;
  const unsigned short* kg0 = Kb + srow * 64 + swz;
  const unsigned short* kg1 = Kb + (srow + 32) * 64 + swz;
  const unsigned short* vg0 = Vb + srow * 1024 + swz;
  const unsigned short* vg1 = Vb + (srow + 32) * 1024 + swz;
  char* pw = (char*)Ps + w * 4096;   // 32 q-rows x 128 B

  const int b = bh >> 4, h = bh & 15;

#pragma unroll 1
  for (int half = 0; half < 2; half++) {
    const int qi = half == 0 ? (7 - pp) : pp;
    const int qw = qi * 128 + w * 32;   // wave's min q
    const int qmax = qw + 31;

    // Q fragments: lane holds Q[qw + qn*16 + lrow][kf*32 + lk*8 + 0..7]
    bf16x8 qf[2][2];
#pragma unroll
    for (int qn = 0; qn < 2; qn++) {
      const unsigned short* qp = Qb + (qw + qn * 16 + lrow) * 64 + lk * 8;
      qf[qn][0] = *(const bf16x8*)qp;
      qf[qn][1] = *(const bf16x8*)(qp + 32);
    }

    f32x4 m[2], lsum[2], yacc[2][4];
#pragma unroll
    for (int qn = 0; qn < 2; qn++) {
      m[qn] = (f32x4){MASKNEG, MASKNEG, MASKNEG, MASKNEG};
      lsum[qn] = (f32x4){0.f, 0.f, 0.f, 0.f};
#pragma unroll
      for (int ef = 0; ef < 4; ef++) yacc[qn][ef] = (f32x4){0.f, 0.f, 0.f, 0.f};
    }

    const int nt = qi * 2 + 2;

    // prologue: stage tile 0 into buffer 0
    {
      char* ksb = (char*)Ks + w * 1024;
      char* vsb = (char*)Vs + w * 1024;
      gload16(kg0, ksb);
      gload16(kg1, ksb + 4096);
      gload16(vg0, vsb);
      gload16(vg1, vsb + 4096);
    }
    __syncthreads();

#pragma unroll 1
    for (int t = 0; t < nt; t++) {
      const int z0 = t * 64;
      const int cur = t & 1;
      if (t < nt - 1) {  // stage next KV tile into other buffer (overlaps compute)
        const int zn = (t + 1) * 64;
        char* ksb = (char*)Ks + (cur ^ 1) * 8192 + w * 1024;
        char* vsb = (char*)Vs + (cur ^ 1) * 8192 + w * 1024;
        gload16(kg0 + zn * 64, ksb);
        gload16(kg1 + zn * 64, ksb + 4096);
        gload16(vg0 + zn, vsb);
        gload16(vg1 + zn, vsb + 4096);
      }

      if (z0 <= qmax) {  // tile has unmasked work for this wave
        const char* kbase = (const char*)Ks + cur * 8192;
        const char* vbase = (const char*)Vs + cur * 8192;

        // S: lane holds S[q = qw + qn*16 + lk*4 + j][z = z0 + zf*16 + lrow]
        f32x4 s[2][4];
#pragma unroll
        for (int qn = 0; qn < 2; qn++)
#pragma unroll
          for (int zf = 0; zf < 4; zf++) s[qn][zf] = (f32x4){0.f, 0.f, 0.f, 0.f};
#pragma unroll
        for (int zf = 0; zf < 4; zf++) {
          int zr = zf * 16 + lrow;
#pragma unroll
          for (int kf = 0; kf < 2; kf++) {
            bf16x8 kfr = *(const bf16x8*)(kbase + zr * 128 + (((kf * 4 + lk) ^ (zr & 7)) << 4));
            s[0][zf] = mfma16(qf[0][kf], kfr, s[0][zf]);
            s[1][zf] = mfma16(qf[1][kf], kfr, s[1][zf]);
          }
        }

        if (z0 + 63 > qw) {  // diagonal overlap: mask z > q (finite sentinel)
#pragma unroll
          for (int qn = 0; qn < 2; qn++) {
            int qbase = qw + qn * 16 + 4 * lk;
#pragma unroll
            for (int zf = 0; zf < 4; zf++) {
              int zg = z0 + zf * 16 + lrow;
#pragma unroll
              for (int j = 0; j < 4; j++)
                if (zg > qbase + j) s[qn][zf][j] = MASKNEG;
            }
          }
        }

        // online softmax per (qn, j): row q = 4*lk + j lives across 16 lanes (lrow) x 4 zf
#pragma unroll
        for (int qn = 0; qn < 2; qn++) {
#pragma unroll
          for (int j = 0; j < 4; j++) {
            float rm = fmaxf(fmaxf(s[qn][0][j], s[qn][1][j]), fmaxf(s[qn][2][j], s[qn][3][j]));
            rm = fmaxf(rm, __shfl_xor(rm, 1));
            rm = fmaxf(rm, __shfl_xor(rm, 2));
            rm = fmaxf(rm, __shfl_xor(rm, 4));
            rm = fmaxf(rm, __shfl_xor(rm, 8));
            float mn = fmaxf(m[qn][j], rm);
            float a = __builtin_amdgcn_exp2f(m[qn][j] - mn);  // <=0 arg
            m[qn][j] = mn;
            lsum[qn][j] *= a;
#pragma unroll
            for (int ef = 0; ef < 4; ef++) yacc[qn][ef][j] *= a;
#pragma unroll
            for (int zf = 0; zf < 4; zf++)
              s[qn][zf][j] = __builtin_amdgcn_exp2f(s[qn][zf][j] - mn);  // <=0 arg
          }

          // P -> per-wave LDS (bf16, round-1 swizzle), row = qn*16 + 4*lk + j
#pragma unroll
          for (int zf = 0; zf < 4; zf++) {
            int zc = zf * 16 + lrow;
            int zp = zc >> 3;
#pragma unroll
            for (int j = 0; j < 4; j++) {
              int q = 4 * lk + j;
              *(unsigned short*)(pw + (qn * 16 + q) * 128 + ((zp ^ (q & 7)) << 4) + (zc & 7) * 2)
                  = f2bf(s[qn][zf][j]);
            }
          }
        }

        // hard wall: DS writes complete, no reordering (TBAA guard for the u16/bf16x8 pun)
        asm volatile("s_waitcnt lgkmcnt(0)" ::: "memory");
        __builtin_amdgcn_sched_barrier(0);

        // read P as A-fragments: lane holds P[q = qn*16 + lrow][z = kf*32 + lk*8 + 0..7]
        bf16x8 pf[2][2];
#pragma unroll
        for (int qn = 0; qn < 2; qn++)
#pragma unroll
          for (int kf = 0; kf < 2; kf++)
            pf[qn][kf] = *(const bf16x8*)(pw + (qn * 16 + lrow) * 128 + (((kf * 4 + lk) ^ (lrow & 7)) << 4));

        // lsum += rowsum(P) via ones-MFMA (D-row = q matches yacc layout; cols uniform)
#pragma unroll
        for (int qn = 0; qn < 2; qn++)
#pragma unroll
          for (int kf = 0; kf < 2; kf++)
            lsum[qn] = mfma16(pf[qn][kf], ones, lsum[qn]);

        // Y += P V  (B-frag: V^T rows e from Vs)
#pragma unroll
        for (int ef = 0; ef < 4; ef++) {
          int er = ef * 16 + lrow;
#pragma unroll
          for (int kf = 0; kf < 2; kf++) {
            bf16x8 vf = *(const bf16x8*)(vbase + er * 128 + (((kf * 4 + lk) ^ (er & 7)) << 4));
            yacc[0][ef] = mfma16(pf[0][kf], vf, yacc[0][ef]);
            yacc[1][ef] = mfma16(pf[1][kf], vf, yacc[1][ef]);
          }
        }
      }

      __syncthreads();  // drains vmcnt: next tile staged; all reads of cur done
    }

    // epilogue: Y[q][e] = yacc / lsum ; q = qw + qn*16 + lk*4 + j, e = ef*16 + lrow
#pragma unroll
    for (int qn = 0; qn < 2; qn++) {
      f32x4 rinv;
#pragma unroll
      for (int j = 0; j < 4; j++) rinv[j] = 1.0f / lsum[qn][j];
#pragma unroll
      for (int ef = 0; ef < 4; ef++) {
        int col = h * 64 + ef * 16 + lrow;
#pragma unroll
        for (int j = 0; j < 4; j++) {
          int x = qw + qn * 16 + lk * 4 + j;
          Y[(b * 1024 + x) * 1024 + col] = f2bf(yacc[qn][ef][j] * rinv[j]);
        }
      }
    }
  }
}

// ---------------- launch ----------------
extern "C" void kernel_launch(void* const* d_in, const int* in_sizes, int n_in,
                              void* d_out, int out_size, void* d_ws, size_t ws_size,
                              hipStream_t stream) {
  const float* x  = (const float*)d_in[0];
  const float* z  = (const float*)d_in[1];
  const float* Wq = (const float*)d_in[2];
  const float* bq = (const float*)d_in[3];
  const float* Wk = (const float*)d_in[4];
  const float* bk = (const float*)d_in[5];
  const float* Wv = (const float*)d_in[6];
  const float* bv = (const float*)d_in[7];
  const float* Wp = (const float*)d_in[8];
  const float* bp = (const float*)d_in[9];
  (void)in_sizes; (void)n_in; (void)out_size; (void)ws_size;

  char* ws = (char*)d_ws;
  unsigned short* Xb  = (unsigned short*)(ws + 0);         // 16 MB (re-used as Y)
  unsigned short* Zb  = (unsigned short*)(ws + 16777216);  // 16 MB
  unsigned short* Wqt = (unsigned short*)(ws + 33554432);  // 2 MB  -- Wqt/Wkt/Wvt contiguous = Wqkv
  unsigned short* Wkt = (unsigned short*)(ws + 35651584);  // 2 MB
  unsigned short* Wvt = (unsigned short*)(ws + 37748736);  // 2 MB
  unsigned short* Wpt = (unsigned short*)(ws + 39845888);  // 2 MB
  unsigned short* Qp  = (unsigned short*)(ws + 41943040);  // 16 MB
  unsigned short* Kp  = (unsigned short*)(ws + 58720256);  // 16 MB
  unsigned short* Vtp = (unsigned short*)(ws + 75497472);  // 16 MB

  k_cvt<<<dim3(2048), dim3(256), 0, stream>>>(x, Xb, 1048576);
  k_cvt<<<dim3(2048), dim3(256), 0, stream>>>(z, Zb, 1048576);
  k_packw<<<dim3(16, 3), dim3(256), 0, stream>>>(Wq, Wk, Wv, Wqt, Wkt, Wvt);
  k_packp<<<dim3(16, 16), dim3(256), 0, stream>>>(Wp, Wpt);

  k_gemm_qkv<<<dim3(64, 24), dim3(256), 0, stream>>>(Xb, Zb, Wqt, bq, bk, bv, Qp, Kp, Vtp);

  k_attn<<<dim3(4, 128), dim3(256), 0, stream>>>(Qp, Kp, Vtp, Xb /*Y*/);

  k_gemm<<<dim3(64, 8), dim3(256), 0, stream>>>(Xb, Wpt, bp, d_out, 3, 1.0f);
}

// Round 7
// 175.174 us; speedup vs baseline: 1.6055x; 1.2592x over previous
//
#include <hip/hip_runtime.h>
#include <stdint.h>

// Pipeline: cvt x,z -> bf16 (1 launch); pack all weights (1 launch, 1024 blocks);
// fused QKV GEMM (bf16 MFMA, 2-phase dbuf); flash attention (causal, paired q-blocks,
// 2-phase dbuf); output GEMM -> f32.
// B=8 TX=TZ=1024 DX=DZ=1024 DATT=DMID=64 H=16 DOUT=1024.

typedef float    f32x4  __attribute__((ext_vector_type(4)));
typedef __bf16   bf16x8 __attribute__((ext_vector_type(8)));
typedef unsigned short u16x4 __attribute__((ext_vector_type(4)));
typedef unsigned short u16x8 __attribute__((ext_vector_type(8)));

#define MASKNEG (-3.0e38f)
#define QSCALE_F (0.125f * 1.4426950408889634f)

__device__ __forceinline__ unsigned short f2bf(float f) {
  unsigned int u = __float_as_uint(f);
  u += 0x7fffu + ((u >> 16) & 1u);   // RNE
  return (unsigned short)(u >> 16);
}

__device__ __forceinline__ void gload16(const void* g, void* s) {
  const __attribute__((address_space(1))) unsigned int* gp =
      (const __attribute__((address_space(1))) unsigned int*)(uintptr_t)g;
  __attribute__((address_space(3))) unsigned int* lp =
      (__attribute__((address_space(3))) unsigned int*)(unsigned int)(uintptr_t)s;
  __builtin_amdgcn_global_load_lds(gp, lp, 16, 0, 0);
}

__device__ __forceinline__ f32x4 mfma16(bf16x8 a, bf16x8 b, f32x4 c) {
  return __builtin_amdgcn_mfma_f32_16x16x32_bf16(a, b, c, 0, 0, 0);
}

// ---------------- prep kernels ----------------

// x and z -> bf16 into contiguous Xb|Zb (Zb = Xb + 8Mi shorts). One launch.
__global__ __launch_bounds__(256) void k_cvt2(const float* __restrict__ x,
                                              const float* __restrict__ z,
                                              unsigned short* __restrict__ out) {
  int i = blockIdx.x * 256 + threadIdx.x;
  const int stride = gridDim.x * 256;
  for (; i < 2097152; i += stride) {
    const float* in = (i < 1048576) ? (x + (size_t)i * 8) : (z + (size_t)(i - 1048576) * 8);
    const f32x4* p = (const f32x4*)in;
    f32x4 a = p[0], b = p[1];
    u16x8 o;
    o[0] = f2bf(a[0]); o[1] = f2bf(a[1]); o[2] = f2bf(a[2]); o[3] = f2bf(a[3]);
    o[4] = f2bf(b[0]); o[5] = f2bf(b[1]); o[6] = f2bf(b[2]); o[7] = f2bf(b[3]);
    *(u16x8*)(out + (size_t)i * 8) = o;
  }
}

// All weight packs in one launch, grid (16,16,4):
//  z<3: Wq/Wk/Wv [H][DX][64] f32 -> O [h*64+e][DX] bf16 (64x64 tile at (h, d0))
//  z=3: Wp [1024][1024] f32 -> Op [n][k] bf16 (64x64 tile at (k0, n0))
__global__ __launch_bounds__(256) void k_pack(const float* __restrict__ Wq,
                                              const float* __restrict__ Wk,
                                              const float* __restrict__ Wv,
                                              const float* __restrict__ Wp,
                                              unsigned short* __restrict__ Oq,
                                              unsigned short* __restrict__ Ok,
                                              unsigned short* __restrict__ Ov,
                                              unsigned short* __restrict__ Op) {
  __shared__ float tile[64][65];
  const int t = threadIdx.x;
  const int zid = blockIdx.z;
  if (zid < 3) {
    const float* W = zid == 0 ? Wq : (zid == 1 ? Wk : Wv);
    unsigned short* O = zid == 0 ? Oq : (zid == 1 ? Ok : Ov);
    const int h = blockIdx.x, d0 = blockIdx.y * 64;
    const int ee = t & 63, r0 = t >> 6;
#pragma unroll
    for (int dd = r0; dd < 64; dd += 4)
      tile[dd][ee] = W[(h * 1024 + d0 + dd) * 64 + ee];
    __syncthreads();
    const int d = t & 63, e0 = t >> 6;
#pragma unroll
    for (int e = e0; e < 64; e += 4)
      O[(h * 64 + e) * 1024 + d0 + d] = f2bf(tile[d][e]);
  } else {
    const int k0 = blockIdx.x * 64, n0 = blockIdx.y * 64;
    const int nn = t & 63, r0 = t >> 6;
#pragma unroll
    for (int kk = r0; kk < 64; kk += 4)
      tile[kk][nn] = Wp[(k0 + kk) * 1024 + n0 + nn];
    __syncthreads();
    const int kk = t & 63, e0 = t >> 6;
#pragma unroll
    for (int n2 = e0; n2 < 64; n2 += 4)
      Op[(n0 + n2) * 1024 + k0 + kk] = f2bf(tile[kk][n2]);
  }
}

// ---------------- GEMM body: C[128x128 tile] = A * Bt^T + bias ----------------
// 2-phase double-buffered: stage kt+1 while computing kt; ONE barrier per K-step.
// As/Bs: 8192 shorts each (2 buffers x 4096).
// mode 0: bf16 out to [bh][x][64] (Q/K), scaled by oscale
// mode 2: bf16 out to [bh][e][z]  (V transposed)
// mode 3: f32 out, row-major (final projection)
__device__ __forceinline__ void gemm_body(const unsigned short* __restrict__ A,
                                          const unsigned short* __restrict__ Bt,
                                          const float* __restrict__ bias,
                                          void* __restrict__ outp,
                                          int mode, float oscale,
                                          int brow, int bcol,
                                          unsigned short* As, unsigned short* Bs) {
  const int tid = threadIdx.x;
  const int l = tid & 63, w = tid >> 6;
  const int lrow = l & 15, lk = l >> 4;
  const int wr = (w >> 1) * 64, wc = (w & 1) * 64;

  const int arow = tid >> 2;
  const int asrc = ((tid & 3) ^ ((arow >> 1) & 3)) * 8;
  const unsigned short* ag0 = A + (brow + arow) * 1024 + asrc;
  const unsigned short* ag1 = ag0 + 64 * 1024;
  const unsigned short* bg0 = Bt + (bcol + arow) * 1024 + asrc;
  const unsigned short* bg1 = bg0 + 64 * 1024;

  int aoff[4], boff[4];
#pragma unroll
  for (int m = 0; m < 4; m++) {
    int row = wr + m * 16 + lrow;
    aoff[m] = row * 64 + ((lk ^ ((row >> 1) & 3)) << 4);
    int col = wc + m * 16 + lrow;
    boff[m] = col * 64 + ((lk ^ ((col >> 1) & 3)) << 4);
  }

  f32x4 acc[4][4];
#pragma unroll
  for (int n = 0; n < 4; n++) {
    float bv = bias[bcol + wc + n * 16 + lrow];
#pragma unroll
    for (int m = 0; m < 4; m++) acc[m][n] = (f32x4){bv, bv, bv, bv};
  }

  // prologue: stage kt=0 into buffer 0
  {
    char* asb = (char*)As + w * 1024;
    char* bsb = (char*)Bs + w * 1024;
    gload16(ag0, asb);
    gload16(ag1, asb + 4096);
    gload16(bg0, bsb);
    gload16(bg1, bsb + 4096);
  }
  __syncthreads();

#pragma unroll 2
  for (int kt = 0; kt < 32; kt++) {
    const int cur = kt & 1;
    if (kt < 31) {  // stage next tile into the other buffer (overlaps MFMA below)
      char* asb = (char*)As + (cur ^ 1) * 8192 + w * 1024;
      char* bsb = (char*)Bs + (cur ^ 1) * 8192 + w * 1024;
      gload16(ag0 + (kt + 1) * 32, asb);
      gload16(ag1 + (kt + 1) * 32, asb + 4096);
      gload16(bg0 + (kt + 1) * 32, bsb);
      gload16(bg1 + (kt + 1) * 32, bsb + 4096);
    }
    const char* ab = (const char*)As + cur * 8192;
    const char* bb = (const char*)Bs + cur * 8192;
    bf16x8 af[4], bfr[4];
#pragma unroll
    for (int m = 0; m < 4; m++) af[m] = *(const bf16x8*)(ab + aoff[m]);
#pragma unroll
    for (int n = 0; n < 4; n++) bfr[n] = *(const bf16x8*)(bb + boff[n]);
#pragma unroll
    for (int m = 0; m < 4; m++)
#pragma unroll
      for (int n = 0; n < 4; n++)
        acc[m][n] = mfma16(af[m], bfr[n], acc[m][n]);
    __syncthreads();  // drains vmcnt(0): next tile staged; all reads of cur done
  }

  if (mode == 0) {
    unsigned short* C = (unsigned short*)outp;
#pragma unroll
    for (int m = 0; m < 4; m++) {
      int r = brow + wr + m * 16 + 4 * lk;
#pragma unroll
      for (int n = 0; n < 4; n++) {
        int c = bcol + wc + n * 16 + lrow;
        unsigned short* p = C + ((r >> 10) * 16 + (c >> 6)) * 65536 + (r & 1023) * 64 + (c & 63);
#pragma unroll
        for (int j = 0; j < 4; j++) p[j * 64] = f2bf(acc[m][n][j] * oscale);
      }
    }
  } else if (mode == 2) {
    unsigned short* C = (unsigned short*)outp;
#pragma unroll
    for (int m = 0; m < 4; m++) {
      int r = brow + wr + m * 16 + 4 * lk;
#pragma unroll
      for (int n = 0; n < 4; n++) {
        int c = bcol + wc + n * 16 + lrow;
        u16x4 o;
#pragma unroll
        for (int j = 0; j < 4; j++) o[j] = f2bf(acc[m][n][j]);
        *(u16x4*)(C + ((r >> 10) * 16 + (c >> 6)) * 65536 + (c & 63) * 1024 + (r & 1023)) = o;
      }
    }
  } else {
    float* C = (float*)outp;
#pragma unroll
    for (int m = 0; m < 4; m++) {
      int r = brow + wr + m * 16 + 4 * lk;
#pragma unroll
      for (int n = 0; n < 4; n++) {
        int c = bcol + wc + n * 16 + lrow;
#pragma unroll
        for (int j = 0; j < 4; j++) C[(r + j) * 1024 + c] = acc[m][n][j];
      }
    }
  }
}

// fused QKV: grid (64, 24); y>>3 = segment (0=Q,1=K,2=V), y&7 = col tile
__global__ __launch_bounds__(256) void k_gemm_qkv(const unsigned short* __restrict__ Xb,
                                                  const unsigned short* __restrict__ Zb,
                                                  const unsigned short* __restrict__ Wqkv,
                                                  const float* __restrict__ bq,
                                                  const float* __restrict__ bk,
                                                  const float* __restrict__ bv,
                                                  unsigned short* __restrict__ Qp,
                                                  unsigned short* __restrict__ Kp,
                                                  unsigned short* __restrict__ Vtp) {
  __shared__ unsigned short As[8192];
  __shared__ unsigned short Bs[8192];
  const int brow = blockIdx.x * 128;
  const int cg = blockIdx.y;
  const int seg = cg >> 3;
  const int bcol = (cg & 7) * 128;
  const unsigned short* A = (seg == 0) ? Xb : Zb;
  const unsigned short* Bt = Wqkv + (size_t)seg * 1048576;
  const float* bias = (seg == 0) ? bq : (seg == 1 ? bk : bv);
  void* outp = (seg == 0) ? (void*)Qp : (seg == 1 ? (void*)Kp : (void*)Vtp);
  const int mode = (seg == 2) ? 2 : 0;
  const float oscale = (seg == 0) ? QSCALE_F : 1.0f;
  gemm_body(A, Bt, bias, outp, mode, oscale, brow, bcol, As, Bs);
}

// final projection: C = Y * Wpt^T + bp (f32 out)
__global__ __launch_bounds__(256) void k_gemm(const unsigned short* __restrict__ A,
                                              const unsigned short* __restrict__ Bt,
                                              const float* __restrict__ bias,
                                              void* __restrict__ outp,
                                              int mode, float oscale) {
  __shared__ unsigned short As[8192];
  __shared__ unsigned short Bs[8192];
  gemm_body(A, Bt, bias, outp, mode, oscale, blockIdx.x * 128, blockIdx.y * 128, As, Bs);
}

// ---------------- flash attention (round-1 orientation, paired q-blocks, 2-phase) ----------------
// Q [bh][1024][64] (prescaled by 0.125*log2e), K [bh][1024][64], Vt [bh][64][1024]
// -> Y [b*1024+x][h*64+e] bf16. Causal.
// Block handles q-blocks qi=7-p and qi=p (constant 18 KV-tiles -> balanced grid).
// Within a q-block: 4 waves x 32 q (2 x 16-row fragments). KV tiles of 64, double-buffered.
// S = mfma(Qfrag, Kfrag): D row = q (lk*4+j), D col = z (zf*16+lrow). Round-1 validated.
__global__ __launch_bounds__(256) void k_attn(const unsigned short* __restrict__ Qh,
                                              const unsigned short* __restrict__ Kh,
                                              const unsigned short* __restrict__ Vth,
                                              unsigned short* __restrict__ Y) {
  __shared__ unsigned short Ks[8192];  // 2 x (64 z x 64 d), swizzled (16 KB)
  __shared__ unsigned short Vs[8192];  // 2 x (64 e x 64 z), swizzled (16 KB)
  __shared__ unsigned short Ps[8192];  // 4 waves x (32 q x 64 z), swizzled (16 KB)

  const int tid = threadIdx.x, l = tid & 63, w = tid >> 6;
  const int lrow = l & 15, lk = l >> 4;
  const int bh = blockIdx.y;
  const int pp = blockIdx.x;       // 0..3 -> handles qi = 7-pp then qi = pp

  const unsigned short* Qb = Qh + bh * 65536;
  const unsigned short* Kb = Kh + bh * 65536;
  const unsigned short* Vb = Vth + bh * 65536;

  // ones B-fragment for lsum-via-MFMA (element-wise init)
  bf16x8 ones;
#pragma unroll
  for (int j = 0; j < 8; j++) ones[j] = (__bf16)1.0f;

  const int srow = tid >> 3;
  const int swz = ((tid & 7) ^ (srow & 7)) * 8;
  const unsigned short* kg0 = Kb + srow * 64 + swz;
  const unsigned short* kg1 = Kb + (srow + 32) * 64 + swz;
  const unsigned short* vg0 = Vb + srow * 1024 + swz;
  const unsigned short* vg1 = Vb + (srow + 32) * 1024 + swz;
  char* pw = (char*)Ps + w * 4096;   // 32 q-rows x 128 B

  const int b = bh >> 4, h = bh & 15;

#pragma unroll 1
  for (int half = 0; half < 2; half++) {
    const int qi = half == 0 ? (7 - pp) : pp;
    const int qw = qi * 128 + w * 32;   // wave's min q
    const int qmax = qw + 31;

    // Q fragments: lane holds Q[qw + qn*16 + lrow][kf*32 + lk*8 + 0..7]
    bf16x8 qf[2][2];
#pragma unroll
    for (int qn = 0; qn < 2; qn++) {
      const unsigned short* qp = Qb + (qw + qn * 16 + lrow) * 64 + lk * 8;
      qf[qn][0] = *(const bf16x8*)qp;
      qf[qn][1] = *(const bf16x8*)(qp + 32);
    }

    f32x4 m[2], lsum[2], yacc[2][4];
#pragma unroll
    for (int qn = 0; qn < 2; qn++) {
      m[qn] = (f32x4){MASKNEG, MASKNEG, MASKNEG, MASKNEG};
      lsum[qn] = (f32x4){0.f, 0.f, 0.f, 0.f};
#pragma unroll
      for (int ef = 0; ef < 4; ef++) yacc[qn][ef] = (f32x4){0.f, 0.f, 0.f, 0.f};
    }

    const int nt = qi * 2 + 2;

    // prologue: stage tile 0 into buffer 0
    {
      char* ksb = (char*)Ks + w * 1024;
      char* vsb = (char*)Vs + w * 1024;
      gload16(kg0, ksb);
      gload16(kg1, ksb + 4096);
      gload16(vg0, vsb);
      gload16(vg1, vsb + 4096);
    }
    __syncthreads();

#pragma unroll 1
    for (int t = 0; t < nt; t++) {
      const int z0 = t * 64;
      const int cur = t & 1;
      if (t < nt - 1) {  // stage next KV tile into other buffer (overlaps compute)
        const int zn = (t + 1) * 64;
        char* ksb = (char*)Ks + (cur ^ 1) * 8192 + w * 1024;
        char* vsb = (char*)Vs + (cur ^ 1) * 8192 + w * 1024;
        gload16(kg0 + zn * 64, ksb);
        gload16(kg1 + zn * 64, ksb + 4096);
        gload16(vg0 + zn, vsb);
        gload16(vg1 + zn, vsb + 4096);
      }

      if (z0 <= qmax) {  // tile has unmasked work for this wave
        const char* kbase = (const char*)Ks + cur * 8192;
        const char* vbase = (const char*)Vs + cur * 8192;

        // S: lane holds S[q = qw + qn*16 + lk*4 + j][z = z0 + zf*16 + lrow]
        f32x4 s[2][4];
#pragma unroll
        for (int qn = 0; qn < 2; qn++)
#pragma unroll
          for (int zf = 0; zf < 4; zf++) s[qn][zf] = (f32x4){0.f, 0.f, 0.f, 0.f};
#pragma unroll
        for (int zf = 0; zf < 4; zf++) {
          int zr = zf * 16 + lrow;
#pragma unroll
          for (int kf = 0; kf < 2; kf++) {
            bf16x8 kfr = *(const bf16x8*)(kbase + zr * 128 + (((kf * 4 + lk) ^ (zr & 7)) << 4));
            s[0][zf] = mfma16(qf[0][kf], kfr, s[0][zf]);
            s[1][zf] = mfma16(qf[1][kf], kfr, s[1][zf]);
          }
        }

        if (z0 + 63 > qw) {  // diagonal overlap: mask z > q (finite sentinel)
#pragma unroll
          for (int qn = 0; qn < 2; qn++) {
            int qbase = qw + qn * 16 + 4 * lk;
#pragma unroll
            for (int zf = 0; zf < 4; zf++) {
              int zg = z0 + zf * 16 + lrow;
#pragma unroll
              for (int j = 0; j < 4; j++)
                if (zg > qbase + j) s[qn][zf][j] = MASKNEG;
            }
          }
        }

        // online softmax per (qn, j): row q = 4*lk + j lives across 16 lanes (lrow) x 4 zf
#pragma unroll
        for (int qn = 0; qn < 2; qn++) {
#pragma unroll
          for (int j = 0; j < 4; j++) {
            float rm = fmaxf(fmaxf(s[qn][0][j], s[qn][1][j]), fmaxf(s[qn][2][j], s[qn][3][j]));
            rm = fmaxf(rm, __shfl_xor(rm, 1));
            rm = fmaxf(rm, __shfl_xor(rm, 2));
            rm = fmaxf(rm, __shfl_xor(rm, 4));
            rm = fmaxf(rm, __shfl_xor(rm, 8));
            float mn = fmaxf(m[qn][j], rm);
            float a = __builtin_amdgcn_exp2f(m[qn][j] - mn);  // <=0 arg
            m[qn][j] = mn;
            lsum[qn][j] *= a;
#pragma unroll
            for (int ef = 0; ef < 4; ef++) yacc[qn][ef][j] *= a;
#pragma unroll
            for (int zf = 0; zf < 4; zf++)
              s[qn][zf][j] = __builtin_amdgcn_exp2f(s[qn][zf][j] - mn);  // <=0 arg
          }

          // P -> per-wave LDS (bf16, round-1 swizzle), row = qn*16 + 4*lk + j
#pragma unroll
          for (int zf = 0; zf < 4; zf++) {
            int zc = zf * 16 + lrow;
            int zp = zc >> 3;
#pragma unroll
            for (int j = 0; j < 4; j++) {
              int q = 4 * lk + j;
              *(unsigned short*)(pw + (qn * 16 + q) * 128 + ((zp ^ (q & 7)) << 4) + (zc & 7) * 2)
                  = f2bf(s[qn][zf][j]);
            }
          }
        }

        // hard wall: DS writes complete, no reordering (TBAA guard for the u16/bf16x8 pun)
        asm volatile("s_waitcnt lgkmcnt(0)" ::: "memory");
        __builtin_amdgcn_sched_barrier(0);

        // read P as A-fragments: lane holds P[q = qn*16 + lrow][z = kf*32 + lk*8 + 0..7]
        bf16x8 pf[2][2];
#pragma unroll
        for (int qn = 0; qn < 2; qn++)
#pragma unroll
          for (int kf = 0; kf < 2; kf++)
            pf[qn][kf] = *(const bf16x8*)(pw + (qn * 16 + lrow) * 128 + (((kf * 4 + lk) ^ (lrow & 7)) << 4));

        // lsum += rowsum(P) via ones-MFMA (D-row = q matches yacc layout; cols uniform)
#pragma unroll
        for (int qn = 0; qn < 2; qn++)
#pragma unroll
          for (int kf = 0; kf < 2; kf++)
            lsum[qn] = mfma16(pf[qn][kf], ones, lsum[qn]);

        // Y += P V  (B-frag: V^T rows e from Vs)
#pragma unroll
        for (int ef = 0; ef < 4; ef++) {
          int er = ef * 16 + lrow;
#pragma unroll
          for (int kf = 0; kf < 2; kf++) {
            bf16x8 vf = *(const bf16x8*)(vbase + er * 128 + (((kf * 4 + lk) ^ (er & 7)) << 4));
            yacc[0][ef] = mfma16(pf[0][kf], vf, yacc[0][ef]);
            yacc[1][ef] = mfma16(pf[1][kf], vf, yacc[1][ef]);
          }
        }
      }

      __syncthreads();  // drains vmcnt: next tile staged; all reads of cur done
    }

    // epilogue: Y[q][e] = yacc / lsum ; q = qw + qn*16 + lk*4 + j, e = ef*16 + lrow
#pragma unroll
    for (int qn = 0; qn < 2; qn++) {
      f32x4 rinv;
#pragma unroll
      for (int j = 0; j < 4; j++) rinv[j] = 1.0f / lsum[qn][j];
#pragma unroll
      for (int ef = 0; ef < 4; ef++) {
        int col = h * 64 + ef * 16 + lrow;
#pragma unroll
        for (int j = 0; j < 4; j++) {
          int x = qw + qn * 16 + lk * 4 + j;
          Y[(b * 1024 + x) * 1024 + col] = f2bf(yacc[qn][ef][j] * rinv[j]);
        }
      }
    }
  }
}

// ---------------- launch ----------------
extern "C" void kernel_launch(void* const* d_in, const int* in_sizes, int n_in,
                              void* d_out, int out_size, void* d_ws, size_t ws_size,
                              hipStream_t stream) {
  const float* x  = (const float*)d_in[0];
  const float* z  = (const float*)d_in[1];
  const float* Wq = (const float*)d_in[2];
  const float* bq = (const float*)d_in[3];
  const float* Wk = (const float*)d_in[4];
  const float* bk = (const float*)d_in[5];
  const float* Wv = (const float*)d_in[6];
  const float* bv = (const float*)d_in[7];
  const float* Wp = (const float*)d_in[8];
  const float* bp = (const float*)d_in[9];
  (void)in_sizes; (void)n_in; (void)out_size; (void)ws_size;

  char* ws = (char*)d_ws;
  unsigned short* Xb  = (unsigned short*)(ws + 0);         // 16 MB (re-used as Y); Zb contiguous after
  unsigned short* Zb  = (unsigned short*)(ws + 16777216);  // 16 MB
  unsigned short* Wqt = (unsigned short*)(ws + 33554432);  // 2 MB  -- Wqt/Wkt/Wvt contiguous = Wqkv
  unsigned short* Wkt = (unsigned short*)(ws + 35651584);  // 2 MB
  unsigned short* Wvt = (unsigned short*)(ws + 37748736);  // 2 MB
  unsigned short* Wpt = (unsigned short*)(ws + 39845888);  // 2 MB
  unsigned short* Qp  = (unsigned short*)(ws + 41943040);  // 16 MB
  unsigned short* Kp  = (unsigned short*)(ws + 58720256);  // 16 MB
  unsigned short* Vtp = (unsigned short*)(ws + 75497472);  // 16 MB

  k_cvt2<<<dim3(2048), dim3(256), 0, stream>>>(x, z, Xb);
  k_pack<<<dim3(16, 16, 4), dim3(256), 0, stream>>>(Wq, Wk, Wv, Wp, Wqt, Wkt, Wvt, Wpt);

  k_gemm_qkv<<<dim3(64, 24), dim3(256), 0, stream>>>(Xb, Zb, Wqt, bq, bk, bv, Qp, Kp, Vtp);

  k_attn<<<dim3(4, 128), dim3(256), 0, stream>>>(Qp, Kp, Vtp, Xb /*Y*/);

  k_gemm<<<dim3(64, 8), dim3(256), 0, stream>>>(Xb, Wpt, bp, d_out, 3, 1.0f);
}

// Round 8
// 171.851 us; speedup vs baseline: 1.6366x; 1.0193x over previous
//
#include <hip/hip_runtime.h>
#include <stdint.h>

// Pipeline: cvt x,z -> bf16 (1 launch); pack all weights (1 launch, 1024 blocks);
// fused QKV GEMM (bf16 MFMA, 3-slot ring, counted-vmcnt pipeline); flash attention
// (causal, paired q-blocks, 2-phase dbuf); output GEMM -> f32.
// B=8 TX=TZ=1024 DX=DZ=1024 DATT=DMID=64 H=16 DOUT=1024.

typedef float    f32x4  __attribute__((ext_vector_type(4)));
typedef __bf16   bf16x8 __attribute__((ext_vector_type(8)));
typedef unsigned short u16x4 __attribute__((ext_vector_type(4)));
typedef unsigned short u16x8 __attribute__((ext_vector_type(8)));

#define MASKNEG (-3.0e38f)
#define QSCALE_F (0.125f * 1.4426950408889634f)

__device__ __forceinline__ unsigned short f2bf(float f) {
  unsigned int u = __float_as_uint(f);
  u += 0x7fffu + ((u >> 16) & 1u);   // RNE
  return (unsigned short)(u >> 16);
}

__device__ __forceinline__ void gload16(const void* g, void* s) {
  const __attribute__((address_space(1))) unsigned int* gp =
      (const __attribute__((address_space(1))) unsigned int*)(uintptr_t)g;
  __attribute__((address_space(3))) unsigned int* lp =
      (__attribute__((address_space(3))) unsigned int*)(unsigned int)(uintptr_t)s;
  __builtin_amdgcn_global_load_lds(gp, lp, 16, 0, 0);
}

__device__ __forceinline__ f32x4 mfma16(bf16x8 a, bf16x8 b, f32x4 c) {
  return __builtin_amdgcn_mfma_f32_16x16x32_bf16(a, b, c, 0, 0, 0);
}

// ---------------- prep kernels ----------------

// x and z -> bf16 into contiguous Xb|Zb (Zb = Xb + 8Mi shorts). One launch.
__global__ __launch_bounds__(256) void k_cvt2(const float* __restrict__ x,
                                              const float* __restrict__ z,
                                              unsigned short* __restrict__ out) {
  int i = blockIdx.x * 256 + threadIdx.x;
  const int stride = gridDim.x * 256;
  for (; i < 2097152; i += stride) {
    const float* in = (i < 1048576) ? (x + (size_t)i * 8) : (z + (size_t)(i - 1048576) * 8);
    const f32x4* p = (const f32x4*)in;
    f32x4 a = p[0], b = p[1];
    u16x8 o;
    o[0] = f2bf(a[0]); o[1] = f2bf(a[1]); o[2] = f2bf(a[2]); o[3] = f2bf(a[3]);
    o[4] = f2bf(b[0]); o[5] = f2bf(b[1]); o[6] = f2bf(b[2]); o[7] = f2bf(b[3]);
    *(u16x8*)(out + (size_t)i * 8) = o;
  }
}

// All weight packs in one launch, grid (16,16,4):
//  z<3: Wq/Wk/Wv [H][DX][64] f32 -> O [h*64+e][DX] bf16 (64x64 tile at (h, d0))
//  z=3: Wp [1024][1024] f32 -> Op [n][k] bf16 (64x64 tile at (k0, n0))
__global__ __launch_bounds__(256) void k_pack(const float* __restrict__ Wq,
                                              const float* __restrict__ Wk,
                                              const float* __restrict__ Wv,
                                              const float* __restrict__ Wp,
                                              unsigned short* __restrict__ Oq,
                                              unsigned short* __restrict__ Ok,
                                              unsigned short* __restrict__ Ov,
                                              unsigned short* __restrict__ Op) {
  __shared__ float tile[64][65];
  const int t = threadIdx.x;
  const int zid = blockIdx.z;
  if (zid < 3) {
    const float* W = zid == 0 ? Wq : (zid == 1 ? Wk : Wv);
    unsigned short* O = zid == 0 ? Oq : (zid == 1 ? Ok : Ov);
    const int h = blockIdx.x, d0 = blockIdx.y * 64;
    const int ee = t & 63, r0 = t >> 6;
#pragma unroll
    for (int dd = r0; dd < 64; dd += 4)
      tile[dd][ee] = W[(h * 1024 + d0 + dd) * 64 + ee];
    __syncthreads();
    const int d = t & 63, e0 = t >> 6;
#pragma unroll
    for (int e = e0; e < 64; e += 4)
      O[(h * 64 + e) * 1024 + d0 + d] = f2bf(tile[d][e]);
  } else {
    const int k0 = blockIdx.x * 64, n0 = blockIdx.y * 64;
    const int nn = t & 63, r0 = t >> 6;
#pragma unroll
    for (int kk = r0; kk < 64; kk += 4)
      tile[kk][nn] = Wp[(k0 + kk) * 1024 + n0 + nn];
    __syncthreads();
    const int kk = t & 63, e0 = t >> 6;
#pragma unroll
    for (int n2 = e0; n2 < 64; n2 += 4)
      Op[(n0 + n2) * 1024 + k0 + kk] = f2bf(tile[kk][n2]);
  }
}

// ---------------- GEMM body: C[128x128 tile] = A * Bt^T + bias ----------------
// 3-slot ring, counted-vmcnt pipeline (T3+T4): issue tile kt+2 at top; bottom waits
// only vmcnt(4) (tile kt+1 done, kt+2 stays in flight across the RAW barrier).
// As/Bs: 12288 shorts each (3 slots x 4096 shorts = 8192 B). 48 KB LDS total.
// mode 0: bf16 out to [bh][x][64] (Q/K), scaled by oscale
// mode 2: bf16 out to [bh][e][z]  (V transposed)
// mode 3: f32 out, row-major (final projection)
__device__ __forceinline__ void gemm_body(const unsigned short* __restrict__ A,
                                          const unsigned short* __restrict__ Bt,
                                          const float* __restrict__ bias,
                                          void* __restrict__ outp,
                                          int mode, float oscale,
                                          int brow, int bcol,
                                          unsigned short* As, unsigned short* Bs) {
  const int tid = threadIdx.x;
  const int l = tid & 63, w = tid >> 6;
  const int lrow = l & 15, lk = l >> 4;
  const int wr = (w >> 1) * 64, wc = (w & 1) * 64;

  const int arow = tid >> 2;
  const int asrc = ((tid & 3) ^ ((arow >> 1) & 3)) * 8;
  const unsigned short* ag0 = A + (brow + arow) * 1024 + asrc;
  const unsigned short* ag1 = ag0 + 64 * 1024;
  const unsigned short* bg0 = Bt + (bcol + arow) * 1024 + asrc;
  const unsigned short* bg1 = bg0 + 64 * 1024;

  int aoff[4], boff[4];
#pragma unroll
  for (int m = 0; m < 4; m++) {
    int row = wr + m * 16 + lrow;
    aoff[m] = row * 64 + ((lk ^ ((row >> 1) & 3)) << 4);
    int col = wc + m * 16 + lrow;
    boff[m] = col * 64 + ((lk ^ ((col >> 1) & 3)) << 4);
  }

  f32x4 acc[4][4];
#pragma unroll
  for (int n = 0; n < 4; n++) {
    float bv = bias[bcol + wc + n * 16 + lrow];
#pragma unroll
    for (int m = 0; m < 4; m++) acc[m][n] = (f32x4){bv, bv, bv, bv};
  }

  // prologue: stage tiles 0 and 1 into slots 0 and 1 (8 loads in flight)
#pragma unroll
  for (int p = 0; p < 2; p++) {
    char* asb = (char*)As + p * 8192 + w * 1024;
    char* bsb = (char*)Bs + p * 8192 + w * 1024;
    gload16(ag0 + p * 32, asb);
    gload16(ag1 + p * 32, asb + 4096);
    gload16(bg0 + p * 32, bsb);
    gload16(bg1 + p * 32, bsb + 4096);
  }
  asm volatile("s_waitcnt vmcnt(4)" ::: "memory");   // tile 0 landed; tile 1 in flight
  __builtin_amdgcn_s_barrier();
  __builtin_amdgcn_sched_barrier(0);

  int s0 = 0, s2 = 2;   // s0 = kt%3 (compute slot), s2 = (kt+2)%3 (stage slot)
#pragma unroll 1
  for (int kt = 0; kt < 32; kt++) {
    if (kt < 30) {  // stage tile kt+2 into slot s2 (stays in flight across barrier)
      char* asb = (char*)As + s2 * 8192 + w * 1024;
      char* bsb = (char*)Bs + s2 * 8192 + w * 1024;
      gload16(ag0 + (kt + 2) * 32, asb);
      gload16(ag1 + (kt + 2) * 32, asb + 4096);
      gload16(bg0 + (kt + 2) * 32, bsb);
      gload16(bg1 + (kt + 2) * 32, bsb + 4096);
    }
    const char* ab = (const char*)As + s0 * 8192;
    const char* bb = (const char*)Bs + s0 * 8192;
    bf16x8 af[4], bfr[4];
#pragma unroll
    for (int m = 0; m < 4; m++) af[m] = *(const bf16x8*)(ab + aoff[m]);
#pragma unroll
    for (int n = 0; n < 4; n++) bfr[n] = *(const bf16x8*)(bb + boff[n]);
#pragma unroll
    for (int m = 0; m < 4; m++)
#pragma unroll
      for (int n = 0; n < 4; n++)
        acc[m][n] = mfma16(af[m], bfr[n], acc[m][n]);

    if (kt < 31) {  // make tile kt+1 ready; do NOT drain the kt+2 loads
      if (kt < 30) {
        asm volatile("s_waitcnt vmcnt(4)" ::: "memory");
      } else {
        asm volatile("s_waitcnt vmcnt(0)" ::: "memory");  // tail: only tile 31 outstanding
      }
      __builtin_amdgcn_s_barrier();
      __builtin_amdgcn_sched_barrier(0);
    }
    s0 = (s0 == 2) ? 0 : s0 + 1;
    s2 = (s2 == 2) ? 0 : s2 + 1;
  }

  if (mode == 0) {
    unsigned short* C = (unsigned short*)outp;
#pragma unroll
    for (int m = 0; m < 4; m++) {
      int r = brow + wr + m * 16 + 4 * lk;
#pragma unroll
      for (int n = 0; n < 4; n++) {
        int c = bcol + wc + n * 16 + lrow;
        unsigned short* p = C + ((r >> 10) * 16 + (c >> 6)) * 65536 + (r & 1023) * 64 + (c & 63);
#pragma unroll
        for (int j = 0; j < 4; j++) p[j * 64] = f2bf(acc[m][n][j] * oscale);
      }
    }
  } else if (mode == 2) {
    unsigned short* C = (unsigned short*)outp;
#pragma unroll
    for (int m = 0; m < 4; m++) {
      int r = brow + wr + m * 16 + 4 * lk;
#pragma unroll
      for (int n = 0; n < 4; n++) {
        int c = bcol + wc + n * 16 + lrow;
        u16x4 o;
#pragma unroll
        for (int j = 0; j < 4; j++) o[j] = f2bf(acc[m][n][j]);
        *(u16x4*)(C + ((r >> 10) * 16 + (c >> 6)) * 65536 + (c & 63) * 1024 + (r & 1023)) = o;
      }
    }
  } else {
    float* C = (float*)outp;
#pragma unroll
    for (int m = 0; m < 4; m++) {
      int r = brow + wr + m * 16 + 4 * lk;
#pragma unroll
      for (int n = 0; n < 4; n++) {
        int c = bcol + wc + n * 16 + lrow;
#pragma unroll
        for (int j = 0; j < 4; j++) C[(r + j) * 1024 + c] = acc[m][n][j];
      }
    }
  }
}

// fused QKV: grid (64, 24); y>>3 = segment (0=Q,1=K,2=V), y&7 = col tile
__global__ __launch_bounds__(256) void k_gemm_qkv(const unsigned short* __restrict__ Xb,
                                                  const unsigned short* __restrict__ Zb,
                                                  const unsigned short* __restrict__ Wqkv,
                                                  const float* __restrict__ bq,
                                                  const float* __restrict__ bk,
                                                  const float* __restrict__ bv,
                                                  unsigned short* __restrict__ Qp,
                                                  unsigned short* __restrict__ Kp,
                                                  unsigned short* __restrict__ Vtp) {
  __shared__ unsigned short As[12288];
  __shared__ unsigned short Bs[12288];
  const int brow = blockIdx.x * 128;
  const int cg = blockIdx.y;
  const int seg = cg >> 3;
  const int bcol = (cg & 7) * 128;
  const unsigned short* A = (seg == 0) ? Xb : Zb;
  const unsigned short* Bt = Wqkv + (size_t)seg * 1048576;
  const float* bias = (seg == 0) ? bq : (seg == 1 ? bk : bv);
  void* outp = (seg == 0) ? (void*)Qp : (seg == 1 ? (void*)Kp : (void*)Vtp);
  const int mode = (seg == 2) ? 2 : 0;
  const float oscale = (seg == 0) ? QSCALE_F : 1.0f;
  gemm_body(A, Bt, bias, outp, mode, oscale, brow, bcol, As, Bs);
}

// final projection: C = Y * Wpt^T + bp (f32 out)
__global__ __launch_bounds__(256) void k_gemm(const unsigned short* __restrict__ A,
                                              const unsigned short* __restrict__ Bt,
                                              const float* __restrict__ bias,
                                              void* __restrict__ outp,
                                              int mode, float oscale) {
  __shared__ unsigned short As[12288];
  __shared__ unsigned short Bs[12288];
  gemm_body(A, Bt, bias, outp, mode, oscale, blockIdx.x * 128, blockIdx.y * 128, As, Bs);
}

// ---------------- flash attention (round-1 orientation, paired q-blocks, 2-phase) ----------------
// Q [bh][1024][64] (prescaled by 0.125*log2e), K [bh][1024][64], Vt [bh][64][1024]
// -> Y [b*1024+x][h*64+e] bf16. Causal.
// Block handles q-blocks qi=7-p and qi=p (constant 18 KV-tiles -> balanced grid).
// Within a q-block: 4 waves x 32 q (2 x 16-row fragments). KV tiles of 64, double-buffered.
// S = mfma(Qfrag, Kfrag): D row = q (lk*4+j), D col = z (zf*16+lrow). Round-1 validated.
__global__ __launch_bounds__(256) void k_attn(const unsigned short* __restrict__ Qh,
                                              const unsigned short* __restrict__ Kh,
                                              const unsigned short* __restrict__ Vth,
                                              unsigned short* __restrict__ Y) {
  __shared__ unsigned short Ks[8192];  // 2 x (64 z x 64 d), swizzled (16 KB)
  __shared__ unsigned short Vs[8192];  // 2 x (64 e x 64 z), swizzled (16 KB)
  __shared__ unsigned short Ps[8192];  // 4 waves x (32 q x 64 z), swizzled (16 KB)

  const int tid = threadIdx.x, l = tid & 63, w = tid >> 6;
  const int lrow = l & 15, lk = l >> 4;
  const int bh = blockIdx.y;
  const int pp = blockIdx.x;       // 0..3 -> handles qi = 7-pp then qi = pp

  const unsigned short* Qb = Qh + bh * 65536;
  const unsigned short* Kb = Kh + bh * 65536;
  const unsigned short* Vb = Vth + bh * 65536;

  // ones B-fragment for lsum-via-MFMA (element-wise init)
  bf16x8 ones;
#pragma unroll
  for (int j = 0; j < 8; j++) ones[j] = (__bf16)1.0f;

  const int srow = tid >> 3;
  const int swz = ((tid & 7) ^ (srow & 7)) * 8;
  const unsigned short* kg0 = Kb + srow * 64 + swz;
  const unsigned short* kg1 = Kb + (srow + 32) * 64 + swz;
  const unsigned short* vg0 = Vb + srow * 1024 + swz;
  const unsigned short* vg1 = Vb + (srow + 32) * 1024 + swz;
  char* pw = (char*)Ps + w * 4096;   // 32 q-rows x 128 B

  const int b = bh >> 4, h = bh & 15;

#pragma unroll 1
  for (int half = 0; half < 2; half++) {
    const int qi = half == 0 ? (7 - pp) : pp;
    const int qw = qi * 128 + w * 32;   // wave's min q
    const int qmax = qw + 31;

    // Q fragments: lane holds Q[qw + qn*16 + lrow][kf*32 + lk*8 + 0..7]
    bf16x8 qf[2][2];
#pragma unroll
    for (int qn = 0; qn < 2; qn++) {
      const unsigned short* qp = Qb + (qw + qn * 16 + lrow) * 64 + lk * 8;
      qf[qn][0] = *(const bf16x8*)qp;
      qf[qn][1] = *(const bf16x8*)(qp + 32);
    }

    f32x4 m[2], lsum[2], yacc[2][4];
#pragma unroll
    for (int qn = 0; qn < 2; qn++) {
      m[qn] = (f32x4){MASKNEG, MASKNEG, MASKNEG, MASKNEG};
      lsum[qn] = (f32x4){0.f, 0.f, 0.f, 0.f};
#pragma unroll
      for (int ef = 0; ef < 4; ef++) yacc[qn][ef] = (f32x4){0.f, 0.f, 0.f, 0.f};
    }

    const int nt = qi * 2 + 2;

    // prologue: stage tile 0 into buffer 0
    {
      char* ksb = (char*)Ks + w * 1024;
      char* vsb = (char*)Vs + w * 1024;
      gload16(kg0, ksb);
      gload16(kg1, ksb + 4096);
      gload16(vg0, vsb);
      gload16(vg1, vsb + 4096);
    }
    __syncthreads();

#pragma unroll 1
    for (int t = 0; t < nt; t++) {
      const int z0 = t * 64;
      const int cur = t & 1;
      if (t < nt - 1) {  // stage next KV tile into other buffer (overlaps compute)
        const int zn = (t + 1) * 64;
        char* ksb = (char*)Ks + (cur ^ 1) * 8192 + w * 1024;
        char* vsb = (char*)Vs + (cur ^ 1) * 8192 + w * 1024;
        gload16(kg0 + zn * 64, ksb);
        gload16(kg1 + zn * 64, ksb + 4096);
        gload16(vg0 + zn, vsb);
        gload16(vg1 + zn, vsb + 4096);
      }

      if (z0 <= qmax) {  // tile has unmasked work for this wave
        const char* kbase = (const char*)Ks + cur * 8192;
        const char* vbase = (const char*)Vs + cur * 8192;

        // S: lane holds S[q = qw + qn*16 + lk*4 + j][z = z0 + zf*16 + lrow]
        f32x4 s[2][4];
#pragma unroll
        for (int qn = 0; qn < 2; qn++)
#pragma unroll
          for (int zf = 0; zf < 4; zf++) s[qn][zf] = (f32x4){0.f, 0.f, 0.f, 0.f};
#pragma unroll
        for (int zf = 0; zf < 4; zf++) {
          int zr = zf * 16 + lrow;
#pragma unroll
          for (int kf = 0; kf < 2; kf++) {
            bf16x8 kfr = *(const bf16x8*)(kbase + zr * 128 + (((kf * 4 + lk) ^ (zr & 7)) << 4));
            s[0][zf] = mfma16(qf[0][kf], kfr, s[0][zf]);
            s[1][zf] = mfma16(qf[1][kf], kfr, s[1][zf]);
          }
        }

        if (z0 + 63 > qw) {  // diagonal overlap: mask z > q (finite sentinel)
#pragma unroll
          for (int qn = 0; qn < 2; qn++) {
            int qbase = qw + qn * 16 + 4 * lk;
#pragma unroll
            for (int zf = 0; zf < 4; zf++) {
              int zg = z0 + zf * 16 + lrow;
#pragma unroll
              for (int j = 0; j < 4; j++)
                if (zg > qbase + j) s[qn][zf][j] = MASKNEG;
            }
          }
        }

        // online softmax per (qn, j): row q = 4*lk + j lives across 16 lanes (lrow) x 4 zf
#pragma unroll
        for (int qn = 0; qn < 2; qn++) {
#pragma unroll
          for (int j = 0; j < 4; j++) {
            float rm = fmaxf(fmaxf(s[qn][0][j], s[qn][1][j]), fmaxf(s[qn][2][j], s[qn][3][j]));
            rm = fmaxf(rm, __shfl_xor(rm, 1));
            rm = fmaxf(rm, __shfl_xor(rm, 2));
            rm = fmaxf(rm, __shfl_xor(rm, 4));
            rm = fmaxf(rm, __shfl_xor(rm, 8));
            float mn = fmaxf(m[qn][j], rm);
            float a = __builtin_amdgcn_exp2f(m[qn][j] - mn);  // <=0 arg
            m[qn][j] = mn;
            lsum[qn][j] *= a;
#pragma unroll
            for (int ef = 0; ef < 4; ef++) yacc[qn][ef][j] *= a;
#pragma unroll
            for (int zf = 0; zf < 4; zf++)
              s[qn][zf][j] = __builtin_amdgcn_exp2f(s[qn][zf][j] - mn);  // <=0 arg
          }

          // P -> per-wave LDS (bf16, round-1 swizzle), row = qn*16 + 4*lk + j
#pragma unroll
          for (int zf = 0; zf < 4; zf++) {
            int zc = zf * 16 + lrow;
            int zp = zc >> 3;
#pragma unroll
            for (int j = 0; j < 4; j++) {
              int q = 4 * lk + j;
              *(unsigned short*)(pw + (qn * 16 + q) * 128 + ((zp ^ (q & 7)) << 4) + (zc & 7) * 2)
                  = f2bf(s[qn][zf][j]);
            }
          }
        }

        // hard wall: DS writes complete, no reordering (TBAA guard for the u16/bf16x8 pun)
        asm volatile("s_waitcnt lgkmcnt(0)" ::: "memory");
        __builtin_amdgcn_sched_barrier(0);

        // read P as A-fragments: lane holds P[q = qn*16 + lrow][z = kf*32 + lk*8 + 0..7]
        bf16x8 pf[2][2];
#pragma unroll
        for (int qn = 0; qn < 2; qn++)
#pragma unroll
          for (int kf = 0; kf < 2; kf++)
            pf[qn][kf] = *(const bf16x8*)(pw + (qn * 16 + lrow) * 128 + (((kf * 4 + lk) ^ (lrow & 7)) << 4));

        // lsum += rowsum(P) via ones-MFMA (D-row = q matches yacc layout; cols uniform)
#pragma unroll
        for (int qn = 0; qn < 2; qn++)
#pragma unroll
          for (int kf = 0; kf < 2; kf++)
            lsum[qn] = mfma16(pf[qn][kf], ones, lsum[qn]);

        // Y += P V  (B-frag: V^T rows e from Vs)
#pragma unroll
        for (int ef = 0; ef < 4; ef++) {
          int er = ef * 16 + lrow;
#pragma unroll
          for (int kf = 0; kf < 2; kf++) {
            bf16x8 vf = *(const bf16x8*)(vbase + er * 128 + (((kf * 4 + lk) ^ (er & 7)) << 4));
            yacc[0][ef] = mfma16(pf[0][kf], vf, yacc[0][ef]);
            yacc[1][ef] = mfma16(pf[1][kf], vf, yacc[1][ef]);
          }
        }
      }

      __syncthreads();  // drains vmcnt: next tile staged; all reads of cur done
    }

    // epilogue: Y[q][e] = yacc / lsum ; q = qw + qn*16 + lk*4 + j, e = ef*16 + lrow
#pragma unroll
    for (int qn = 0; qn < 2; qn++) {
      f32x4 rinv;
#pragma unroll
      for (int j = 0; j < 4; j++) rinv[j] = 1.0f / lsum[qn][j];
#pragma unroll
      for (int ef = 0; ef < 4; ef++) {
        int col = h * 64 + ef * 16 + lrow;
#pragma unroll
        for (int j = 0; j < 4; j++) {
          int x = qw + qn * 16 + lk * 4 + j;
          Y[(b * 1024 + x) * 1024 + col] = f2bf(yacc[qn][ef][j] * rinv[j]);
        }
      }
    }
  }
}

// ---------------- launch ----------------
extern "C" void kernel_launch(void* const* d_in, const int* in_sizes, int n_in,
                              void* d_out, int out_size, void* d_ws, size_t ws_size,
                              hipStream_t stream) {
  const float* x  = (const float*)d_in[0];
  const float* z  = (const float*)d_in[1];
  const float* Wq = (const float*)d_in[2];
  const float* bq = (const float*)d_in[3];
  const float* Wk = (const float*)d_in[4];
  const float* bk = (const float*)d_in[5];
  const float* Wv = (const float*)d_in[6];
  const float* bv = (const float*)d_in[7];
  const float* Wp = (const float*)d_in[8];
  const float* bp = (const float*)d_in[9];
  (void)in_sizes; (void)n_in; (void)out_size; (void)ws_size;

  char* ws = (char*)d_ws;
  unsigned short* Xb  = (unsigned short*)(ws + 0);         // 16 MB (re-used as Y); Zb contiguous after
  unsigned short* Zb  = (unsigned short*)(ws + 16777216);  // 16 MB
  unsigned short* Wqt = (unsigned short*)(ws + 33554432);  // 2 MB  -- Wqt/Wkt/Wvt contiguous = Wqkv
  unsigned short* Wkt = (unsigned short*)(ws + 35651584);  // 2 MB
  unsigned short* Wvt = (unsigned short*)(ws + 37748736);  // 2 MB
  unsigned short* Wpt = (unsigned short*)(ws + 39845888);  // 2 MB
  unsigned short* Qp  = (unsigned short*)(ws + 41943040);  // 16 MB
  unsigned short* Kp  = (unsigned short*)(ws + 58720256);  // 16 MB
  unsigned short* Vtp = (unsigned short*)(ws + 75497472);  // 16 MB

  k_cvt2<<<dim3(2048), dim3(256), 0, stream>>>(x, z, Xb);
  k_pack<<<dim3(16, 16, 4), dim3(256), 0, stream>>>(Wq, Wk, Wv, Wp, Wqt, Wkt, Wvt, Wpt);

  k_gemm_qkv<<<dim3(64, 24), dim3(256), 0, stream>>>(Xb, Zb, Wqt, bq, bk, bv, Qp, Kp, Vtp);

  k_attn<<<dim3(4, 128), dim3(256), 0, stream>>>(Qp, Kp, Vtp, Xb /*Y*/);

  k_gemm<<<dim3(64, 8), dim3(256), 0, stream>>>(Xb, Wpt, bp, d_out, 3, 1.0f);
}